// Round 1
// baseline (991.144 us; speedup 1.0000x reference)
//
#include <hip/hip_runtime.h>
#include <math.h>

#define NATOMS 4096
#define FDIM   128
#define NHEAD  4
#define DHEAD  32
#define KNBR   15
#define NKER   50
#define NLAYER 6
#define QKVW   640   // 128 q + 128 k + 384 v

__device__ __forceinline__ float silu_f(float x) { return x / (1.0f + expf(-x)); }

// ---------------------------------------------------------------------------
// Kernel 1: KNN (iterative argmin over full distance row) + edge features
// one block per atom, 256 threads
// ---------------------------------------------------------------------------
__global__ __launch_bounds__(256) void knn_kernel(
    const float* __restrict__ R, const float* __restrict__ batch,
    int* __restrict__ idxs, float* __restrict__ cutw,
    float* __restrict__ vecn, float* __restrict__ ebuf)
{
    __shared__ float d2s[NATOMS];
    __shared__ float rv[256];
    __shared__ int   ri_[256];
    __shared__ int   sel[KNBR];
    const int i = blockIdx.x, t = threadIdx.x;
    const float xi = R[i*3+0], yi = R[i*3+1], zi = R[i*3+2];
    const float bi = batch[i];
    const float sqi = xi*xi + yi*yi + zi*zi;
    for (int j = t; j < NATOMS; j += 256) {
        float xj = R[j*3+0], yj = R[j*3+1], zj = R[j*3+2];
        float sqj = xj*xj + yj*yj + zj*zj;
        float d2 = sqi + sqj - 2.0f*(xi*xj + yi*yj + zi*zj);
        if (bi*batch[j] == 0.0f || j == i) d2 = 1e9f;
        else d2 = fmaxf(d2, 0.0f);
        d2s[j] = d2;
    }
    __syncthreads();
    for (int k = 0; k < KNBR; ++k) {
        float best = 1e30f; int bidx = 0x7fffffff;
        for (int j = t; j < NATOMS; j += 256) {
            float v = d2s[j];
            if (v < best) { best = v; bidx = j; }
        }
        rv[t] = best; ri_[t] = bidx;
        __syncthreads();
        for (int off = 128; off > 0; off >>= 1) {
            if (t < off) {
                float v2 = rv[t+off]; int i2 = ri_[t+off];
                if (v2 < rv[t] || (v2 == rv[t] && i2 < ri_[t])) { rv[t] = v2; ri_[t] = i2; }
            }
            __syncthreads();
        }
        if (t == 0) { sel[k] = ri_[0]; d2s[ri_[0]] = 1e9f; }
        __syncthreads();
    }
    if (t < KNBR) {
        int j = sel[t];
        idxs[i*KNBR + t] = j;
        float vx = R[j*3+0]-xi, vy = R[j*3+1]-yi, vz = R[j*3+2]-zi;
        float d = sqrtf(vx*vx + vy*vy + vz*vz + 1e-12f);
        float inv = 1.0f/d;
        vecn[(i*KNBR+t)*3+0] = vx*inv;
        vecn[(i*KNBR+t)*3+1] = vy*inv;
        vecn[(i*KNBR+t)*3+2] = vz*inv;
        const float PI = 3.14159265358979323846f;
        float cutv = (d <= 5.0f) ? 0.5f*(cosf(PI*d*0.2f) + 1.0f) : 0.0f;
        cutw[i*KNBR + t] = cutv;
        for (int jj = 0; jj < NKER; ++jj) {
            float mu = 5.0f * (float)jj / 49.0f;
            float dd = d - mu;
            ebuf[(i*KNBR+t)*NKER + jj] = expf(-dd*dd*50.0f) * cutv;
        }
    }
}

// ---------------------------------------------------------------------------
// Kernel 2: init s = emb[Z], o = 0, v0 = 0
// ---------------------------------------------------------------------------
__global__ __launch_bounds__(256) void init_kernel(
    const int* __restrict__ Z, const float* __restrict__ emb,
    float* __restrict__ s, float* __restrict__ o, float* __restrict__ v0)
{
    int stride = gridDim.x * blockDim.x;
    for (int idx = blockIdx.x*blockDim.x + threadIdx.x; idx < NATOMS*3*FDIM; idx += stride) {
        v0[idx] = 0.0f;
        if (idx < NATOMS*FDIM) {
            int a = idx >> 7, c = idx & 127;
            s[idx] = emb[Z[a]*FDIM + c];
            o[idx] = 0.0f;
        }
    }
}

// ---------------------------------------------------------------------------
// Kernel 3: per-layer QKV projection  qkv = s @ [Wq | Wk | Wv]
// tiled fp32 GEMM, M=4096 N=640 K=128, 64x64 tiles, 4x4 per thread
// grid (64, 10), 256 threads
// ---------------------------------------------------------------------------
__global__ __launch_bounds__(256) void proj_kernel(
    const float* __restrict__ S, const float* __restrict__ Wq,
    const float* __restrict__ Wk, const float* __restrict__ Wv,
    float* __restrict__ QKV, int l)
{
    __shared__ float As[16][68];
    __shared__ float Bs[16][68];
    const int bmi = blockIdx.x, bni = blockIdx.y;
    const float* W; int ldw, nc0;
    if (bni < 2)      { W = Wq + l*128*128; ldw = 128; nc0 = bni*64; }
    else if (bni < 4) { W = Wk + l*128*128; ldw = 128; nc0 = (bni-2)*64; }
    else              { W = Wv + l*128*384; ldw = 384; nc0 = (bni-4)*64; }
    const int t = threadIdx.x;
    const int tn = t & 15, tm = t >> 4;
    float acc[4][4] = {};
    for (int k0 = 0; k0 < 128; k0 += 16) {
        for (int x = t; x < 1024; x += 256) {
            int m = x >> 4, kk = x & 15;
            As[kk][m] = S[(bmi*64+m)*FDIM + k0 + kk];
        }
        for (int x = t; x < 1024; x += 256) {
            int kk = x >> 6, n = x & 63;
            Bs[kk][n] = W[(k0+kk)*ldw + nc0 + n];
        }
        __syncthreads();
        #pragma unroll
        for (int kk = 0; kk < 16; ++kk) {
            float a[4], b[4];
            #pragma unroll
            for (int u = 0; u < 4; ++u) a[u] = As[kk][tm*4+u];
            #pragma unroll
            for (int u = 0; u < 4; ++u) b[u] = Bs[kk][tn*4+u];
            #pragma unroll
            for (int u = 0; u < 4; ++u)
                #pragma unroll
                for (int w = 0; w < 4; ++w) acc[u][w] += a[u]*b[w];
        }
        __syncthreads();
    }
    int row0 = bmi*64 + tm*4, col0 = bni*64 + tn*4;
    for (int u = 0; u < 4; ++u)
        for (int w = 0; w < 4; ++w)
            QKV[(row0+u)*QKVW + col0 + w] = acc[u][w];
}

// ---------------------------------------------------------------------------
// Kernel 4: fused edge-filter GEMM + attention + aggregation (one block/atom)
// ---------------------------------------------------------------------------
__global__ __launch_bounds__(256) void attn_kernel(
    const float* __restrict__ QKV, const int* __restrict__ idxs,
    const float* __restrict__ cutw, const float* __restrict__ vecn,
    const float* __restrict__ ebuf,
    const float* __restrict__ WeK, const float* __restrict__ beK,
    const float* __restrict__ WeV, const float* __restrict__ beV,
    float* __restrict__ s, float* __restrict__ o,
    const float* __restrict__ vin, float* __restrict__ vout, int l)
{
    __shared__ float e_s[KNBR][NKER];
    __shared__ float khs[KNBR][FDIM];      // kk rows, then kh = kk*ek in place
    __shared__ float mvs[KNBR][3*FDIM];    // val rows, then m = val*ev in place
    __shared__ float qv[FDIM];
    __shared__ float vnc[KNBR][3];
    __shared__ float cutv[KNBR];
    __shared__ float lgs[KNBR][NHEAD];
    __shared__ float attns[KNBR][NHEAD];
    __shared__ int   nidx[KNBR];
    const int i = blockIdx.x, t = threadIdx.x;

    if (t < KNBR) {
        nidx[t] = idxs[i*KNBR + t];
        cutv[t] = cutw[i*KNBR + t];
        vnc[t][0] = vecn[(i*KNBR+t)*3+0];
        vnc[t][1] = vecn[(i*KNBR+t)*3+1];
        vnc[t][2] = vecn[(i*KNBR+t)*3+2];
    }
    for (int x = t; x < KNBR*NKER; x += 256) e_s[x/NKER][x%NKER] = ebuf[i*KNBR*NKER + x];
    if (t < FDIM) qv[t] = QKV[i*QKVW + t];
    __syncthreads();

    for (int x = t; x < KNBR*FDIM; x += 256) {
        int k = x >> 7, c = x & 127;
        khs[k][c] = QKV[nidx[k]*QKVW + FDIM + c];
    }
    for (int x = t; x < KNBR*3*FDIM; x += 256) {
        int k = x / 384, c = x % 384;
        mvs[k][c] = QKV[nidx[k]*QKVW + 2*FDIM + c];
    }
    __syncthreads();

    // --- edge filter GEMM (e @ We + be, silu) fused with kk/val multiply ---
    {
        const float* Wp0; int ld0, c0; float b0;
        if (t < 128) { Wp0 = WeK + l*NKER*FDIM;  ld0 = FDIM;  c0 = t;     b0 = beK[l*FDIM + t]; }
        else         { Wp0 = WeV + l*NKER*3*FDIM; ld0 = 3*FDIM; c0 = t-128; b0 = beV[l*3*FDIM + t-128]; }
        const float* Wp1 = WeV + l*NKER*3*FDIM;
        const int c1 = t + 128;
        const float b1 = beV[l*3*FDIM + c1];
        float acc0[KNBR], acc1[KNBR];
        #pragma unroll
        for (int k = 0; k < KNBR; ++k) { acc0[k] = b0; acc1[k] = b1; }
        for (int j = 0; j < NKER; ++j) {
            float w0 = Wp0[j*ld0 + c0];
            float w1 = Wp1[j*384 + c1];
            #pragma unroll
            for (int k = 0; k < KNBR; ++k) {
                float e = e_s[k][j];
                acc0[k] += e*w0;
                acc1[k] += e*w1;
            }
        }
        #pragma unroll
        for (int k = 0; k < KNBR; ++k) {
            float f0 = silu_f(acc0[k]);
            float f1 = silu_f(acc1[k]);
            if (t < 128) khs[k][t] *= f0; else mvs[k][t-128] *= f0;
            mvs[k][c1] *= f1;
        }
    }
    __syncthreads();

    // --- logits: q . kh per (k, h) ---
    if (t < KNBR*NHEAD) {
        int k = t / NHEAD, h = t % NHEAD;
        float acc = 0.0f;
        #pragma unroll
        for (int d = 0; d < DHEAD; ++d) acc += qv[h*DHEAD+d] * khs[k][h*DHEAD+d];
        lgs[k][h] = acc * 0.125f;   // 1/sqrt(32*2)
    }
    __syncthreads();

    // --- softmax over k per head, times cutoff ---
    if (t < NHEAD) {
        float m = -1e30f;
        for (int k = 0; k < KNBR; ++k) m = fmaxf(m, lgs[k][t]);
        float ssum = 0.0f;
        for (int k = 0; k < KNBR; ++k) ssum += expf(lgs[k][t]-m);
        float inv = 1.0f / ssum;
        for (int k = 0; k < KNBR; ++k) attns[k][t] = expf(lgs[k][t]-m)*inv*cutv[k];
    }
    __syncthreads();

    // --- aggregate messages: ds (128) and dv (3x128) ---
    for (int ix = t; ix < 512; ix += 256) {
        if (ix < 128) {
            int c = ix, h = c >> 5;
            float ds = 0.0f;
            #pragma unroll
            for (int k = 0; k < KNBR; ++k) ds += attns[k][h]*mvs[k][c];
            s[i*FDIM+c] += ds;
            o[i*FDIM+c] += ds;
        } else {
            int xc = ix - 128;
            int x = xc >> 7, c = xc & 127, h = c >> 5;
            float dv = 0.0f;
            #pragma unroll
            for (int k = 0; k < KNBR; ++k) {
                float w = attns[k][h];
                dv += w * (mvs[k][FDIM+c]*vnc[k][x]
                         + mvs[k][2*FDIM+c]*vin[nidx[k]*3*FDIM + x*FDIM + c]);
            }
            vout[i*3*FDIM + xc] = vin[i*3*FDIM + xc] + dv;
        }
    }
}

// ---------------------------------------------------------------------------
// Kernel 5: zero output, then LayerNorm + readout, atomicAdd per atom
// ---------------------------------------------------------------------------
__global__ void zero_kernel(float* out) { out[0] = 0.0f; }

__global__ __launch_bounds__(128) void final_kernel(
    const float* __restrict__ o, const float* __restrict__ lng, const float* __restrict__ lnb,
    const float* __restrict__ Wo1, const float* __restrict__ Wo2,
    const float* __restrict__ batch, float* __restrict__ out)
{
    __shared__ float red[128];
    __shared__ float on[128];
    const int i = blockIdx.x, t = threadIdx.x;
    float x = o[i*FDIM + t];
    red[t] = x; __syncthreads();
    for (int off = 64; off > 0; off >>= 1) { if (t < off) red[t] += red[t+off]; __syncthreads(); }
    float mean = red[0] * (1.0f/128.0f);
    __syncthreads();
    float xm = x - mean;
    red[t] = xm*xm; __syncthreads();
    for (int off = 64; off > 0; off >>= 1) { if (t < off) red[t] += red[t+off]; __syncthreads(); }
    float var = red[0] * (1.0f/128.0f);
    __syncthreads();
    on[t] = xm * rsqrtf(var + 1e-5f) * lng[t] + lnb[t];
    __syncthreads();
    float acc = 0.0f;
    #pragma unroll 8
    for (int j = 0; j < 128; ++j) acc += on[j] * Wo1[j*128 + t];
    float h = silu_f(acc) * Wo2[t];
    red[t] = h; __syncthreads();
    for (int off = 64; off > 0; off >>= 1) { if (t < off) red[t] += red[t+off]; __syncthreads(); }
    if (t == 0) atomicAdd(out, red[0] * batch[i]);
}

// ---------------------------------------------------------------------------
extern "C" void kernel_launch(void* const* d_in, const int* in_sizes, int n_in,
                              void* d_out, int out_size, void* d_ws, size_t ws_size,
                              hipStream_t stream)
{
    const int*   Z     = (const int*)  d_in[0];
    const float* R     = (const float*)d_in[1];
    const float* batch = (const float*)d_in[2];
    const float* emb   = (const float*)d_in[3];
    const float* Wq    = (const float*)d_in[4];
    const float* Wk    = (const float*)d_in[5];
    const float* Wv    = (const float*)d_in[6];
    const float* WeK   = (const float*)d_in[7];
    const float* beK   = (const float*)d_in[8];
    const float* WeV   = (const float*)d_in[9];
    const float* beV   = (const float*)d_in[10];
    const float* lng   = (const float*)d_in[11];
    const float* lnb   = (const float*)d_in[12];
    const float* Wo1   = (const float*)d_in[13];
    const float* Wo2   = (const float*)d_in[14];
    float* out = (float*)d_out;

    float* fws = (float*)d_ws;
    float* s    = fws; fws += NATOMS*FDIM;
    float* o    = fws; fws += NATOMS*FDIM;
    float* v0   = fws; fws += NATOMS*3*FDIM;
    float* v1   = fws; fws += NATOMS*3*FDIM;
    float* qkv  = fws; fws += NATOMS*QKVW;
    float* cutw = fws; fws += NATOMS*KNBR;
    float* vecn = fws; fws += NATOMS*KNBR*3;
    float* ebuf = fws; fws += NATOMS*KNBR*NKER;
    int*   idxs = (int*)fws;

    knn_kernel<<<NATOMS, 256, 0, stream>>>(R, batch, idxs, cutw, vecn, ebuf);
    init_kernel<<<1024, 256, 0, stream>>>(Z, emb, s, o, v0);
    for (int l = 0; l < NLAYER; ++l) {
        proj_kernel<<<dim3(64, 10), 256, 0, stream>>>(s, Wq, Wk, Wv, qkv, l);
        float* vin  = (l & 1) ? v1 : v0;
        float* vout = (l & 1) ? v0 : v1;
        attn_kernel<<<NATOMS, 256, 0, stream>>>(qkv, idxs, cutw, vecn, ebuf,
                                                WeK, beK, WeV, beV,
                                                s, o, vin, vout, l);
    }
    zero_kernel<<<1, 1, 0, stream>>>(out);
    final_kernel<<<NATOMS, 128, 0, stream>>>(o, lng, lnb, Wo1, Wo2, batch, out);
}

// Round 2
// 957.829 us; speedup vs baseline: 1.0348x; 1.0348x over previous
//
#include <hip/hip_runtime.h>
#include <math.h>

#define NATOMS 4096
#define FDIM   128
#define NHEAD  4
#define DHEAD  32
#define KNBR   15
#define NKER   50
#define NLAYER 6
#define QKVW   640   // 128 q + 128 k + 384 v

__device__ __forceinline__ float silu_f(float x) { return x / (1.0f + expf(-x)); }

// ---------------------------------------------------------------------------
// Kernel 1: KNN (iterative argmin over full distance row) + edge features
// one block per atom, 256 threads
// ---------------------------------------------------------------------------
__global__ __launch_bounds__(256) void knn_kernel(
    const float* __restrict__ R, const float* __restrict__ batch,
    int* __restrict__ idxs, float* __restrict__ cutw,
    float* __restrict__ vecn, float* __restrict__ ebuf)
{
    __shared__ float d2s[NATOMS];
    __shared__ float rv[256];
    __shared__ int   ri_[256];
    __shared__ int   sel[KNBR];
    const int i = blockIdx.x, t = threadIdx.x;
    const float xi = R[i*3+0], yi = R[i*3+1], zi = R[i*3+2];
    const float bi = batch[i];
    const float sqi = xi*xi + yi*yi + zi*zi;
    for (int j = t; j < NATOMS; j += 256) {
        float xj = R[j*3+0], yj = R[j*3+1], zj = R[j*3+2];
        float sqj = xj*xj + yj*yj + zj*zj;
        float d2 = sqi + sqj - 2.0f*(xi*xj + yi*yj + zi*zj);
        if (bi*batch[j] == 0.0f || j == i) d2 = 1e9f;
        else d2 = fmaxf(d2, 0.0f);
        d2s[j] = d2;
    }
    __syncthreads();
    for (int k = 0; k < KNBR; ++k) {
        float best = 1e30f; int bidx = 0x7fffffff;
        for (int j = t; j < NATOMS; j += 256) {
            float v = d2s[j];
            if (v < best) { best = v; bidx = j; }
        }
        rv[t] = best; ri_[t] = bidx;
        __syncthreads();
        for (int off = 128; off > 0; off >>= 1) {
            if (t < off) {
                float v2 = rv[t+off]; int i2 = ri_[t+off];
                if (v2 < rv[t] || (v2 == rv[t] && i2 < ri_[t])) { rv[t] = v2; ri_[t] = i2; }
            }
            __syncthreads();
        }
        if (t == 0) { sel[k] = ri_[0]; d2s[ri_[0]] = 1e9f; }
        __syncthreads();
    }
    if (t < KNBR) {
        int j = sel[t];
        idxs[i*KNBR + t] = j;
        float vx = R[j*3+0]-xi, vy = R[j*3+1]-yi, vz = R[j*3+2]-zi;
        float d = sqrtf(vx*vx + vy*vy + vz*vz + 1e-12f);
        float inv = 1.0f/d;
        vecn[(i*KNBR+t)*3+0] = vx*inv;
        vecn[(i*KNBR+t)*3+1] = vy*inv;
        vecn[(i*KNBR+t)*3+2] = vz*inv;
        const float PI = 3.14159265358979323846f;
        float cutv = (d <= 5.0f) ? 0.5f*(cosf(PI*d*0.2f) + 1.0f) : 0.0f;
        cutw[i*KNBR + t] = cutv;
        for (int jj = 0; jj < NKER; ++jj) {
            float mu = 5.0f * (float)jj / 49.0f;
            float dd = d - mu;
            ebuf[(i*KNBR+t)*NKER + jj] = expf(-dd*dd*50.0f) * cutv;
        }
    }
}

// ---------------------------------------------------------------------------
// Kernel 2: init s = emb[Z], o = 0, v0 = 0
// ---------------------------------------------------------------------------
__global__ __launch_bounds__(256) void init_kernel(
    const int* __restrict__ Z, const float* __restrict__ emb,
    float* __restrict__ s, float* __restrict__ o, float* __restrict__ v0)
{
    int stride = gridDim.x * blockDim.x;
    for (int idx = blockIdx.x*blockDim.x + threadIdx.x; idx < NATOMS*3*FDIM; idx += stride) {
        v0[idx] = 0.0f;
        if (idx < NATOMS*FDIM) {
            int a = idx >> 7, c = idx & 127;
            s[idx] = emb[Z[a]*FDIM + c];
            o[idx] = 0.0f;
        }
    }
}

// ---------------------------------------------------------------------------
// Kernel 3: per-layer QKV projection  qkv = s @ [Wq | Wk | Wv]
// tiled fp32 GEMM, M=4096 N=640 K=128, 64x64 tiles, 4x4 per thread
// ---------------------------------------------------------------------------
__global__ __launch_bounds__(256) void proj_kernel(
    const float* __restrict__ S, const float* __restrict__ Wq,
    const float* __restrict__ Wk, const float* __restrict__ Wv,
    float* __restrict__ QKV, int l)
{
    __shared__ float As[16][68];
    __shared__ float Bs[16][68];
    const int bmi = blockIdx.x, bni = blockIdx.y;
    const float* W; int ldw, nc0;
    if (bni < 2)      { W = Wq + l*128*128; ldw = 128; nc0 = bni*64; }
    else if (bni < 4) { W = Wk + l*128*128; ldw = 128; nc0 = (bni-2)*64; }
    else              { W = Wv + l*128*384; ldw = 384; nc0 = (bni-4)*64; }
    const int t = threadIdx.x;
    const int tn = t & 15, tm = t >> 4;
    float acc[4][4] = {};
    for (int k0 = 0; k0 < 128; k0 += 16) {
        for (int x = t; x < 1024; x += 256) {
            int m = x >> 4, kk = x & 15;
            As[kk][m] = S[(bmi*64+m)*FDIM + k0 + kk];
        }
        for (int x = t; x < 1024; x += 256) {
            int kk = x >> 6, n = x & 63;
            Bs[kk][n] = W[(k0+kk)*ldw + nc0 + n];
        }
        __syncthreads();
        #pragma unroll
        for (int kk = 0; kk < 16; ++kk) {
            float a[4], b[4];
            #pragma unroll
            for (int u = 0; u < 4; ++u) a[u] = As[kk][tm*4+u];
            #pragma unroll
            for (int u = 0; u < 4; ++u) b[u] = Bs[kk][tn*4+u];
            #pragma unroll
            for (int u = 0; u < 4; ++u)
                #pragma unroll
                for (int w = 0; w < 4; ++w) acc[u][w] += a[u]*b[w];
        }
        __syncthreads();
    }
    int row0 = bmi*64 + tm*4, col0 = bni*64 + tn*4;
    for (int u = 0; u < 4; ++u)
        for (int w = 0; w < 4; ++w)
            QKV[(row0+u)*QKVW + col0 + w] = acc[u][w];
}

// ---------------------------------------------------------------------------
// Kernel 4 (v2): fused edge-filter + attention. 512 threads, one block/atom.
//   t in [0,128):    ek filter col t  -> logits via shfl -> softmax -> attns
//   t in [128,512):  ev filter col c  -> gather val col  -> aggregate
// No big LDS staging: kh/val live in registers; e row read via scalar loads.
// ---------------------------------------------------------------------------
__global__ __launch_bounds__(512, 4) void attn_kernel(
    const float* __restrict__ QKV, const int* __restrict__ idxs,
    const float* __restrict__ cutw, const float* __restrict__ vecn,
    const float* __restrict__ ebuf,
    const float* __restrict__ WeK, const float* __restrict__ beK,
    const float* __restrict__ WeV, const float* __restrict__ beV,
    float* __restrict__ s, float* __restrict__ o,
    const float* __restrict__ vin, float* __restrict__ vout, int l)
{
    __shared__ int   nidx[KNBR];
    __shared__ float cutv[KNBR];
    __shared__ float vnc[KNBR][3];
    __shared__ float attns[KNBR][NHEAD];
    __shared__ float dvbuf[3][FDIM];

    const int i = blockIdx.x, t = threadIdx.x;

    if (t < KNBR) {
        nidx[t] = idxs[i*KNBR + t];
        cutv[t] = cutw[i*KNBR + t];
        vnc[t][0] = vecn[(i*KNBR+t)*3+0];
        vnc[t][1] = vecn[(i*KNBR+t)*3+1];
        vnc[t][2] = vecn[(i*KNBR+t)*3+2];
    }
    __syncthreads();

    const float* __restrict__ erow = ebuf + (size_t)i*(KNBR*NKER);  // wave-uniform -> s_load

    float mval[KNBR];   // value-column messages (t>=128 path)
    int   c = 0, h = 0;

    if (t < FDIM) {
        // ---- key path: ek filter for column t ----
        c = t; h = c >> 5;
        const float* __restrict__ W = WeK + l*NKER*FDIM + c;
        float acc[KNBR];
        const float b = beK[l*FDIM + c];
        #pragma unroll
        for (int k = 0; k < KNBR; ++k) acc[k] = b;
        for (int j = 0; j < NKER; ++j) {
            float w = W[j*FDIM];
            #pragma unroll
            for (int k = 0; k < KNBR; ++k) acc[k] += erow[k*NKER + j] * w;
        }
        const float q = QKV[i*QKVW + c];
        float lg[KNBR];
        #pragma unroll
        for (int k = 0; k < KNBR; ++k) {
            float p = q * QKV[nidx[k]*QKVW + FDIM + c] * silu_f(acc[k]);
            p += __shfl_xor(p, 1);
            p += __shfl_xor(p, 2);
            p += __shfl_xor(p, 4);
            p += __shfl_xor(p, 8);
            p += __shfl_xor(p, 16);          // sum over 32-lane head group
            lg[k] = p * 0.125f;              // 1/sqrt(DH*TEMP)=1/8
        }
        // redundant per-lane softmax over k
        float m = -1e30f;
        #pragma unroll
        for (int k = 0; k < KNBR; ++k) m = fmaxf(m, lg[k]);
        float ssum = 0.0f;
        #pragma unroll
        for (int k = 0; k < KNBR; ++k) { lg[k] = expf(lg[k]-m); ssum += lg[k]; }
        float inv = 1.0f/ssum;
        if ((c & 31) == 0) {
            #pragma unroll
            for (int k = 0; k < KNBR; ++k) attns[k][h] = lg[k]*inv*cutv[k];
        }
    } else {
        // ---- value path: ev filter for column c of 384 ----
        c = t - FDIM; h = (c & 127) >> 5;
        const float* __restrict__ W = WeV + l*NKER*3*FDIM + c;
        float acc[KNBR];
        const float b = beV[l*3*FDIM + c];
        #pragma unroll
        for (int k = 0; k < KNBR; ++k) acc[k] = b;
        for (int j = 0; j < NKER; ++j) {
            float w = W[j*3*FDIM];
            #pragma unroll
            for (int k = 0; k < KNBR; ++k) acc[k] += erow[k*NKER + j] * w;
        }
        #pragma unroll
        for (int k = 0; k < KNBR; ++k)
            mval[k] = QKV[nidx[k]*QKVW + 2*FDIM + c] * silu_f(acc[k]);
    }
    __syncthreads();   // attns published

    if (t >= FDIM) {
        if (c < FDIM) {
            // m1 -> ds
            float ds = 0.0f;
            #pragma unroll
            for (int k = 0; k < KNBR; ++k) ds += attns[k][h]*mval[k];
            s[i*FDIM + c] += ds;
            o[i*FDIM + c] += ds;
        } else if (c < 2*FDIM) {
            // m2 -> dv partial via vec_norm
            const int cc = c - FDIM;
            float d0 = 0.0f, d1 = 0.0f, d2 = 0.0f;
            #pragma unroll
            for (int k = 0; k < KNBR; ++k) {
                float w = attns[k][h]*mval[k];
                d0 += w*vnc[k][0]; d1 += w*vnc[k][1]; d2 += w*vnc[k][2];
            }
            dvbuf[0][cc] = d0; dvbuf[1][cc] = d1; dvbuf[2][cc] = d2;
        }
    }
    float d3[3] = {0.0f, 0.0f, 0.0f};
    if (t >= FDIM && c >= 2*FDIM) {
        // m3 -> dv partial via neighbor v
        const int cc = c - 2*FDIM;
        #pragma unroll
        for (int k = 0; k < KNBR; ++k) {
            float w = attns[k][h]*mval[k];
            const float* vb = vin + (size_t)nidx[k]*3*FDIM + cc;
            d3[0] += w*vb[0*FDIM]; d3[1] += w*vb[1*FDIM]; d3[2] += w*vb[2*FDIM];
        }
    }
    __syncthreads();   // dvbuf ready
    if (t >= FDIM && c >= 2*FDIM) {
        const int cc = c - 2*FDIM;
        #pragma unroll
        for (int x = 0; x < 3; ++x) {
            size_t off = (size_t)i*3*FDIM + x*FDIM + cc;
            vout[off] = vin[off] + dvbuf[x][cc] + d3[x];
        }
    }
}

// ---------------------------------------------------------------------------
// Kernel 5: zero output, then LayerNorm + readout, atomicAdd per atom
// ---------------------------------------------------------------------------
__global__ void zero_kernel(float* out) { out[0] = 0.0f; }

__global__ __launch_bounds__(128) void final_kernel(
    const float* __restrict__ o, const float* __restrict__ lng, const float* __restrict__ lnb,
    const float* __restrict__ Wo1, const float* __restrict__ Wo2,
    const float* __restrict__ batch, float* __restrict__ out)
{
    __shared__ float red[128];
    __shared__ float on[128];
    const int i = blockIdx.x, t = threadIdx.x;
    float x = o[i*FDIM + t];
    red[t] = x; __syncthreads();
    for (int off = 64; off > 0; off >>= 1) { if (t < off) red[t] += red[t+off]; __syncthreads(); }
    float mean = red[0] * (1.0f/128.0f);
    __syncthreads();
    float xm = x - mean;
    red[t] = xm*xm; __syncthreads();
    for (int off = 64; off > 0; off >>= 1) { if (t < off) red[t] += red[t+off]; __syncthreads(); }
    float var = red[0] * (1.0f/128.0f);
    __syncthreads();
    on[t] = xm * rsqrtf(var + 1e-5f) * lng[t] + lnb[t];
    __syncthreads();
    float acc = 0.0f;
    #pragma unroll 8
    for (int j = 0; j < 128; ++j) acc += on[j] * Wo1[j*128 + t];
    float h = silu_f(acc) * Wo2[t];
    red[t] = h; __syncthreads();
    for (int off = 64; off > 0; off >>= 1) { if (t < off) red[t] += red[t+off]; __syncthreads(); }
    if (t == 0) atomicAdd(out, red[0] * batch[i]);
}

// ---------------------------------------------------------------------------
extern "C" void kernel_launch(void* const* d_in, const int* in_sizes, int n_in,
                              void* d_out, int out_size, void* d_ws, size_t ws_size,
                              hipStream_t stream)
{
    const int*   Z     = (const int*)  d_in[0];
    const float* R     = (const float*)d_in[1];
    const float* batch = (const float*)d_in[2];
    const float* emb   = (const float*)d_in[3];
    const float* Wq    = (const float*)d_in[4];
    const float* Wk    = (const float*)d_in[5];
    const float* Wv    = (const float*)d_in[6];
    const float* WeK   = (const float*)d_in[7];
    const float* beK   = (const float*)d_in[8];
    const float* WeV   = (const float*)d_in[9];
    const float* beV   = (const float*)d_in[10];
    const float* lng   = (const float*)d_in[11];
    const float* lnb   = (const float*)d_in[12];
    const float* Wo1   = (const float*)d_in[13];
    const float* Wo2   = (const float*)d_in[14];
    float* out = (float*)d_out;

    float* fws = (float*)d_ws;
    float* s    = fws; fws += NATOMS*FDIM;
    float* o    = fws; fws += NATOMS*FDIM;
    float* v0   = fws; fws += NATOMS*3*FDIM;
    float* v1   = fws; fws += NATOMS*3*FDIM;
    float* qkv  = fws; fws += NATOMS*QKVW;
    float* cutw = fws; fws += NATOMS*KNBR;
    float* vecn = fws; fws += NATOMS*KNBR*3;
    float* ebuf = fws; fws += NATOMS*KNBR*NKER;
    int*   idxs = (int*)fws;

    knn_kernel<<<NATOMS, 256, 0, stream>>>(R, batch, idxs, cutw, vecn, ebuf);
    init_kernel<<<1024, 256, 0, stream>>>(Z, emb, s, o, v0);
    for (int l = 0; l < NLAYER; ++l) {
        proj_kernel<<<dim3(64, 10), 256, 0, stream>>>(s, Wq, Wk, Wv, qkv, l);
        float* vin  = (l & 1) ? v1 : v0;
        float* vout = (l & 1) ? v0 : v1;
        attn_kernel<<<NATOMS, 512, 0, stream>>>(qkv, idxs, cutw, vecn, ebuf,
                                                WeK, beK, WeV, beV,
                                                s, o, vin, vout, l);
    }
    zero_kernel<<<1, 1, 0, stream>>>(out);
    final_kernel<<<NATOMS, 128, 0, stream>>>(o, lng, lnb, Wo1, Wo2, batch, out);
}

// Round 3
// 743.711 us; speedup vs baseline: 1.3327x; 1.2879x over previous
//
#include <hip/hip_runtime.h>
#include <math.h>

#define NATOMS 4096
#define FDIM   128
#define NHEAD  4
#define DHEAD  32
#define KNBR   15
#define NKER   50
#define NLAYER 6
#define QKVW   640   // 128 q + 128 k + 384 v

typedef __attribute__((ext_vector_type(8))) short short8;
typedef __attribute__((ext_vector_type(4))) float f32x4;

__device__ __forceinline__ float silu_f(float x) { return x / (1.0f + expf(-x)); }

// ---------------------------------------------------------------------------
// Kernel 1: KNN (iterative argmin over full distance row) + edge features
// ---------------------------------------------------------------------------
__global__ __launch_bounds__(256) void knn_kernel(
    const float* __restrict__ R, const float* __restrict__ batch,
    int* __restrict__ idxs, float* __restrict__ cutw,
    float* __restrict__ vecn, float* __restrict__ ebuf)
{
    __shared__ float d2s[NATOMS];
    __shared__ float rv[256];
    __shared__ int   ri_[256];
    __shared__ int   sel[KNBR];
    const int i = blockIdx.x, t = threadIdx.x;
    const float xi = R[i*3+0], yi = R[i*3+1], zi = R[i*3+2];
    const float bi = batch[i];
    const float sqi = xi*xi + yi*yi + zi*zi;
    for (int j = t; j < NATOMS; j += 256) {
        float xj = R[j*3+0], yj = R[j*3+1], zj = R[j*3+2];
        float sqj = xj*xj + yj*yj + zj*zj;
        float d2 = sqi + sqj - 2.0f*(xi*xj + yi*yj + zi*zj);
        if (bi*batch[j] == 0.0f || j == i) d2 = 1e9f;
        else d2 = fmaxf(d2, 0.0f);
        d2s[j] = d2;
    }
    __syncthreads();
    for (int k = 0; k < KNBR; ++k) {
        float best = 1e30f; int bidx = 0x7fffffff;
        for (int j = t; j < NATOMS; j += 256) {
            float v = d2s[j];
            if (v < best) { best = v; bidx = j; }
        }
        rv[t] = best; ri_[t] = bidx;
        __syncthreads();
        for (int off = 128; off > 0; off >>= 1) {
            if (t < off) {
                float v2 = rv[t+off]; int i2 = ri_[t+off];
                if (v2 < rv[t] || (v2 == rv[t] && i2 < ri_[t])) { rv[t] = v2; ri_[t] = i2; }
            }
            __syncthreads();
        }
        if (t == 0) { sel[k] = ri_[0]; d2s[ri_[0]] = 1e9f; }
        __syncthreads();
    }
    if (t < KNBR) {
        int j = sel[t];
        idxs[i*KNBR + t] = j;
        float vx = R[j*3+0]-xi, vy = R[j*3+1]-yi, vz = R[j*3+2]-zi;
        float d = sqrtf(vx*vx + vy*vy + vz*vz + 1e-12f);
        float inv = 1.0f/d;
        vecn[(i*KNBR+t)*3+0] = vx*inv;
        vecn[(i*KNBR+t)*3+1] = vy*inv;
        vecn[(i*KNBR+t)*3+2] = vz*inv;
        const float PI = 3.14159265358979323846f;
        float cutv = (d <= 5.0f) ? 0.5f*(cosf(PI*d*0.2f) + 1.0f) : 0.0f;
        cutw[i*KNBR + t] = cutv;
        for (int jj = 0; jj < NKER; ++jj) {
            float mu = 5.0f * (float)jj / 49.0f;
            float dd = d - mu;
            ebuf[(i*KNBR+t)*NKER + jj] = expf(-dd*dd*50.0f) * cutv;
        }
    }
}

// ---------------------------------------------------------------------------
// Kernel 2: init s = emb[Z], o = 0, v0 = 0
// ---------------------------------------------------------------------------
__global__ __launch_bounds__(256) void init_kernel(
    const int* __restrict__ Z, const float* __restrict__ emb,
    float* __restrict__ s, float* __restrict__ o, float* __restrict__ v0)
{
    int stride = gridDim.x * blockDim.x;
    for (int idx = blockIdx.x*blockDim.x + threadIdx.x; idx < NATOMS*3*FDIM; idx += stride) {
        v0[idx] = 0.0f;
        if (idx < NATOMS*FDIM) {
            int a = idx >> 7, c = idx & 127;
            s[idx] = emb[Z[a]*FDIM + c];
            o[idx] = 0.0f;
        }
    }
}

// ---------------------------------------------------------------------------
// Kernel W-prep: swizzle WeK/WeV (fp32) into MFMA B-fragment order, bf16 hi/lo
// blk = ((l*32 + T)*2 + ks); lane holds B[k = ks*32+quad*8+j][col = col0+lx]
// layout: Wswz[blk][part(0=hi,1=lo)][lane][8]  (shorts)
// ---------------------------------------------------------------------------
__global__ __launch_bounds__(64) void wprep_kernel(
    const float* __restrict__ WeK, const float* __restrict__ WeV,
    unsigned short* __restrict__ Wswz)
{
    const int blk = blockIdx.x;
    const int lane = threadIdx.x;
    const int ks = blk & 1;
    const int T  = (blk >> 1) & 31;
    const int l  = blk >> 6;
    const int quad = lane >> 4, x = lane & 15;
    unsigned short* dst = Wswz + (size_t)blk*1024 + lane*8;
    for (int j = 0; j < 8; ++j) {
        int k = ks*32 + quad*8 + j;
        float w = 0.0f;
        if (k < NKER)
            w = (T < 8) ? WeK[l*NKER*FDIM + k*FDIM + T*16 + x]
                        : WeV[(size_t)l*NKER*3*FDIM + k*3*FDIM + (T-8)*16 + x];
        unsigned b = __float_as_uint(w);
        dst[j] = (unsigned short)(b >> 16);                       // hi (truncated bf16)
        float r = w - __uint_as_float(b & 0xFFFF0000u);           // exact residual
        dst[512 + j] = (unsigned short)(__float_as_uint(r) >> 16); // lo
    }
}

// ---------------------------------------------------------------------------
// Kernel 3: per-layer QKV projection  qkv = s @ [Wq | Wk | Wv]
// 64x64 tiles, 4x4 per thread, float4 LDS reads
// ---------------------------------------------------------------------------
__global__ __launch_bounds__(256) void proj_kernel(
    const float* __restrict__ S, const float* __restrict__ Wq,
    const float* __restrict__ Wk, const float* __restrict__ Wv,
    float* __restrict__ QKV, int l)
{
    __shared__ __align__(16) float As[16][68];
    __shared__ __align__(16) float Bs[16][68];
    const int bmi = blockIdx.x, bni = blockIdx.y;
    const float* W; int ldw, nc0;
    if (bni < 2)      { W = Wq + l*128*128; ldw = 128; nc0 = bni*64; }
    else if (bni < 4) { W = Wk + l*128*128; ldw = 128; nc0 = (bni-2)*64; }
    else              { W = Wv + l*128*384; ldw = 384; nc0 = (bni-4)*64; }
    const int t = threadIdx.x;
    const int tn = t & 15, tm = t >> 4;
    float acc[4][4] = {};
    for (int k0 = 0; k0 < 128; k0 += 16) {
        for (int x = t; x < 1024; x += 256) {
            int m = x >> 4, kk = x & 15;
            As[kk][m] = S[(bmi*64+m)*FDIM + k0 + kk];
        }
        for (int x = t; x < 1024; x += 256) {
            int kk = x >> 6, n = x & 63;
            Bs[kk][n] = W[(k0+kk)*ldw + nc0 + n];
        }
        __syncthreads();
        #pragma unroll
        for (int kk = 0; kk < 16; ++kk) {
            f32x4 a4 = *(const f32x4*)&As[kk][tm*4];
            f32x4 b4 = *(const f32x4*)&Bs[kk][tn*4];
            #pragma unroll
            for (int u = 0; u < 4; ++u)
                #pragma unroll
                for (int w = 0; w < 4; ++w) acc[u][w] += a4[u]*b4[w];
        }
        __syncthreads();
    }
    int row0 = bmi*64 + tm*4, col0 = bni*64 + tn*4;
    for (int u = 0; u < 4; ++u)
        for (int w = 0; w < 4; ++w)
            QKV[(row0+u)*QKVW + col0 + w] = acc[u][w];
}

// ---------------------------------------------------------------------------
// Kernel 4 (v3): MFMA edge-filter + attention. 512 threads (8 waves) / atom.
// Phase 1: E[16x64] @ W[64x512] via mfma_f32_16x16x32_bf16, hi/lo fp32 split;
//          epilogue bias+silu, multiply by gathered kk/val, write fbuf LDS.
// Phase 2: logits/softmax (waves 0-1) + message aggregation (R2 structure).
// ---------------------------------------------------------------------------
__global__ __launch_bounds__(512) void attn_kernel(
    const float* __restrict__ QKV, const int* __restrict__ idxs,
    const float* __restrict__ cutw, const float* __restrict__ vecn,
    const float* __restrict__ ebuf, const unsigned short* __restrict__ Wswz,
    const float* __restrict__ beK, const float* __restrict__ beV,
    float* __restrict__ s, float* __restrict__ o,
    const float* __restrict__ vin, float* __restrict__ vout, int l)
{
    __shared__ __align__(16) float es[16][68];    // padded E (fp32)
    __shared__ float fbuf[KNBR][516];             // filtered kh / mval
    __shared__ int   nidx[KNBR];
    __shared__ float cutv[KNBR];
    __shared__ float vnc[KNBR][3];
    __shared__ float attns[KNBR][NHEAD];
    __shared__ float dvbuf[3][FDIM];

    const int i = blockIdx.x, t = threadIdx.x;
    const int wave = t >> 6, lane = t & 63;
    const int quad = lane >> 4, lx = lane & 15;

    if (t < KNBR) {
        nidx[t] = idxs[i*KNBR + t];
        cutv[t] = cutw[i*KNBR + t];
        vnc[t][0] = vecn[(i*KNBR+t)*3+0];
        vnc[t][1] = vecn[(i*KNBR+t)*3+1];
        vnc[t][2] = vecn[(i*KNBR+t)*3+2];
    }
    for (int x = t; x < 16*64; x += 512) {
        int row = x >> 6, col = x & 63;
        es[row][col] = (row < KNBR && col < NKER)
                       ? ebuf[(size_t)i*KNBR*NKER + row*NKER + col] : 0.0f;
    }
    __syncthreads();

    // ---- A fragments: E rows in bf16 hi/lo (A[m=lane&15][k=quad*8+j]) ----
    short8 eh[2], el[2];
    #pragma unroll
    for (int ks = 0; ks < 2; ++ks) {
        float v[8];
        *(f32x4*)&v[0] = *(const f32x4*)&es[lx][ks*32 + quad*8];
        *(f32x4*)&v[4] = *(const f32x4*)&es[lx][ks*32 + quad*8 + 4];
        #pragma unroll
        for (int j = 0; j < 8; ++j) {
            unsigned b = __float_as_uint(v[j]);
            eh[ks][j] = (short)(b >> 16);
            float r = v[j] - __uint_as_float(b & 0xFFFF0000u);
            el[ks][j] = (short)(__float_as_uint(r) >> 16);
        }
    }

    // ---- per-tile MFMA + epilogue ----
    #pragma unroll
    for (int tt = 0; tt < 4; ++tt) {
        const int T = wave*4 + tt;
        const int col = T*16 + lx;
        f32x4 acc = {0.0f, 0.0f, 0.0f, 0.0f};
        #pragma unroll
        for (int ks = 0; ks < 2; ++ks) {
            const unsigned short* wp = Wswz + ((size_t)((l*32+T)*2+ks))*1024 + lane*8;
            short8 bh = *(const short8*)wp;
            short8 bl = *(const short8*)(wp + 512);
            acc = __builtin_amdgcn_mfma_f32_16x16x32_bf16(eh[ks], bh, acc, 0, 0, 0);
            acc = __builtin_amdgcn_mfma_f32_16x16x32_bf16(eh[ks], bl, acc, 0, 0, 0);
            acc = __builtin_amdgcn_mfma_f32_16x16x32_bf16(el[ks], bh, acc, 0, 0, 0);
        }
        const float b = (col < FDIM) ? beK[l*FDIM + col]
                                     : beV[(size_t)l*3*FDIM + (col - FDIM)];
        const int goff = (col < FDIM) ? (FDIM + col) : (2*FDIM + (col - FDIM));
        #pragma unroll
        for (int r = 0; r < 4; ++r) {
            int k = quad*4 + r;
            if (k < KNBR) {
                float f = silu_f(acc[r] + b);
                float g = QKV[(size_t)nidx[k]*QKVW + goff];
                fbuf[k][col] = f * g;
            }
        }
    }
    __syncthreads();   // fbuf complete

    // ---- phase 2: logits + softmax (threads 0..127) ----
    if (t < FDIM) {
        const int c = t, h = c >> 5;
        const float q = QKV[(size_t)i*QKVW + c];
        float lg[KNBR];
        #pragma unroll
        for (int k = 0; k < KNBR; ++k) {
            float p = q * fbuf[k][c];
            p += __shfl_xor(p, 1);
            p += __shfl_xor(p, 2);
            p += __shfl_xor(p, 4);
            p += __shfl_xor(p, 8);
            p += __shfl_xor(p, 16);
            lg[k] = p * 0.125f;
        }
        float m = -1e30f;
        #pragma unroll
        for (int k = 0; k < KNBR; ++k) m = fmaxf(m, lg[k]);
        float ssum = 0.0f;
        #pragma unroll
        for (int k = 0; k < KNBR; ++k) { lg[k] = expf(lg[k]-m); ssum += lg[k]; }
        float inv = 1.0f/ssum;
        if ((c & 31) == 0) {
            #pragma unroll
            for (int k = 0; k < KNBR; ++k) attns[k][h] = lg[k]*inv*cutv[k];
        }
    }
    float mval[KNBR];
    int cv = 0, h2 = 0;
    if (t >= FDIM) {
        cv = t - FDIM; h2 = (cv & 127) >> 5;
        #pragma unroll
        for (int k = 0; k < KNBR; ++k) mval[k] = fbuf[k][FDIM + cv];
    }
    __syncthreads();   // attns published

    if (t >= FDIM) {
        if (cv < FDIM) {
            float ds = 0.0f;
            #pragma unroll
            for (int k = 0; k < KNBR; ++k) ds += attns[k][h2]*mval[k];
            s[i*FDIM + cv] += ds;
            o[i*FDIM + cv] += ds;
        } else if (cv < 2*FDIM) {
            const int cc = cv - FDIM;
            float d0 = 0.0f, d1 = 0.0f, d2 = 0.0f;
            #pragma unroll
            for (int k = 0; k < KNBR; ++k) {
                float w = attns[k][h2]*mval[k];
                d0 += w*vnc[k][0]; d1 += w*vnc[k][1]; d2 += w*vnc[k][2];
            }
            dvbuf[0][cc] = d0; dvbuf[1][cc] = d1; dvbuf[2][cc] = d2;
        }
    }
    float d3[3] = {0.0f, 0.0f, 0.0f};
    if (t >= FDIM && cv >= 2*FDIM) {
        const int cc = cv - 2*FDIM;
        #pragma unroll
        for (int k = 0; k < KNBR; ++k) {
            float w = attns[k][h2]*mval[k];
            const float* vb = vin + (size_t)nidx[k]*3*FDIM + cc;
            d3[0] += w*vb[0*FDIM]; d3[1] += w*vb[1*FDIM]; d3[2] += w*vb[2*FDIM];
        }
    }
    __syncthreads();   // dvbuf ready
    if (t >= FDIM && cv >= 2*FDIM) {
        const int cc = cv - 2*FDIM;
        #pragma unroll
        for (int x = 0; x < 3; ++x) {
            size_t off = (size_t)i*3*FDIM + x*FDIM + cc;
            vout[off] = vin[off] + dvbuf[x][cc] + d3[x];
        }
    }
}

// ---------------------------------------------------------------------------
// Kernel 5: zero output, then LayerNorm + readout, atomicAdd per atom
// ---------------------------------------------------------------------------
__global__ void zero_kernel(float* out) { out[0] = 0.0f; }

__global__ __launch_bounds__(128) void final_kernel(
    const float* __restrict__ o, const float* __restrict__ lng, const float* __restrict__ lnb,
    const float* __restrict__ Wo1, const float* __restrict__ Wo2,
    const float* __restrict__ batch, float* __restrict__ out)
{
    __shared__ float red[128];
    __shared__ float on[128];
    const int i = blockIdx.x, t = threadIdx.x;
    float x = o[i*FDIM + t];
    red[t] = x; __syncthreads();
    for (int off = 64; off > 0; off >>= 1) { if (t < off) red[t] += red[t+off]; __syncthreads(); }
    float mean = red[0] * (1.0f/128.0f);
    __syncthreads();
    float xm = x - mean;
    red[t] = xm*xm; __syncthreads();
    for (int off = 64; off > 0; off >>= 1) { if (t < off) red[t] += red[t+off]; __syncthreads(); }
    float var = red[0] * (1.0f/128.0f);
    __syncthreads();
    on[t] = xm * rsqrtf(var + 1e-5f) * lng[t] + lnb[t];
    __syncthreads();
    float acc = 0.0f;
    #pragma unroll 8
    for (int j = 0; j < 128; ++j) acc += on[j] * Wo1[j*128 + t];
    float h = silu_f(acc) * Wo2[t];
    red[t] = h; __syncthreads();
    for (int off = 64; off > 0; off >>= 1) { if (t < off) red[t] += red[t+off]; __syncthreads(); }
    if (t == 0) atomicAdd(out, red[0] * batch[i]);
}

// ---------------------------------------------------------------------------
extern "C" void kernel_launch(void* const* d_in, const int* in_sizes, int n_in,
                              void* d_out, int out_size, void* d_ws, size_t ws_size,
                              hipStream_t stream)
{
    const int*   Z     = (const int*)  d_in[0];
    const float* R     = (const float*)d_in[1];
    const float* batch = (const float*)d_in[2];
    const float* emb   = (const float*)d_in[3];
    const float* Wq    = (const float*)d_in[4];
    const float* Wk    = (const float*)d_in[5];
    const float* Wv    = (const float*)d_in[6];
    const float* WeK   = (const float*)d_in[7];
    const float* beK   = (const float*)d_in[8];
    const float* WeV   = (const float*)d_in[9];
    const float* beV   = (const float*)d_in[10];
    const float* lng   = (const float*)d_in[11];
    const float* lnb   = (const float*)d_in[12];
    const float* Wo1   = (const float*)d_in[13];
    const float* Wo2   = (const float*)d_in[14];
    float* out = (float*)d_out;

    float* fws = (float*)d_ws;
    float* s    = fws; fws += NATOMS*FDIM;
    float* o    = fws; fws += NATOMS*FDIM;
    float* v0   = fws; fws += NATOMS*3*FDIM;
    float* v1   = fws; fws += NATOMS*3*FDIM;
    float* qkv  = fws; fws += NATOMS*QKVW;
    float* cutw = fws; fws += NATOMS*KNBR;
    float* vecn = fws; fws += NATOMS*KNBR*3;
    float* ebuf = fws; fws += NATOMS*KNBR*NKER;
    int*   idxs = (int*)fws; fws += NATOMS*KNBR;
    unsigned short* Wswz = (unsigned short*)fws;   // 6*32*2*1024 shorts = 768 KB

    wprep_kernel<<<NLAYER*32*2, 64, 0, stream>>>(WeK, WeV, Wswz);
    knn_kernel<<<NATOMS, 256, 0, stream>>>(R, batch, idxs, cutw, vecn, ebuf);
    init_kernel<<<1024, 256, 0, stream>>>(Z, emb, s, o, v0);
    for (int l = 0; l < NLAYER; ++l) {
        proj_kernel<<<dim3(64, 10), 256, 0, stream>>>(s, Wq, Wk, Wv, qkv, l);
        float* vin  = (l & 1) ? v1 : v0;
        float* vout = (l & 1) ? v0 : v1;
        attn_kernel<<<NATOMS, 512, 0, stream>>>(qkv, idxs, cutw, vecn, ebuf, Wswz,
                                                beK, beV, s, o, vin, vout, l);
    }
    zero_kernel<<<1, 1, 0, stream>>>(out);
    final_kernel<<<NATOMS, 128, 0, stream>>>(o, lng, lnb, Wo1, Wo2, batch, out);
}

// Round 4
// 621.632 us; speedup vs baseline: 1.5944x; 1.1964x over previous
//
#include <hip/hip_runtime.h>
#include <math.h>

#define NATOMS 4096
#define FDIM   128
#define NHEAD  4
#define DHEAD  32
#define KNBR   15
#define NKER   50
#define NLAYER 6
#define QKVW   640   // 128 q + 128 k + 384 v

typedef __attribute__((ext_vector_type(8))) short short8;
typedef __attribute__((ext_vector_type(4))) float f32x4;

__device__ __forceinline__ float silu_f(float x) { return x / (1.0f + __expf(-x)); }

__device__ __forceinline__ unsigned long long shfl_xor_u64(unsigned long long v, int m) {
    unsigned lo = (unsigned)v, hi = (unsigned)(v >> 32);
    lo = (unsigned)__shfl_xor((int)lo, m);
    hi = (unsigned)__shfl_xor((int)hi, m);
    return ((unsigned long long)hi << 32) | lo;
}
__device__ __forceinline__ unsigned long long min_u64(unsigned long long a, unsigned long long b) {
    return a < b ? a : b;
}

// ---------------------------------------------------------------------------
// Kernel 1 (v2): KNN via packed-u64 shuffle argmin (1 barrier/round) + edges
// ---------------------------------------------------------------------------
__global__ __launch_bounds__(256) void knn_kernel(
    const float* __restrict__ R, const float* __restrict__ batch,
    int* __restrict__ idxs, float* __restrict__ cutw,
    float* __restrict__ vecn, float* __restrict__ ebuf)
{
    __shared__ float d2s[NATOMS];
    __shared__ unsigned long long wred[2][4];
    __shared__ int sel[KNBR];
    const int i = blockIdx.x, t = threadIdx.x;
    const int wave = t >> 6, lane = t & 63;
    const float xi = R[i*3+0], yi = R[i*3+1], zi = R[i*3+2];
    const float bi = batch[i];
    const float sqi = xi*xi + yi*yi + zi*zi;
    for (int j = t; j < NATOMS; j += 256) {
        float xj = R[j*3+0], yj = R[j*3+1], zj = R[j*3+2];
        float sqj = xj*xj + yj*yj + zj*zj;
        float d2 = sqi + sqj - 2.0f*(xi*xj + yi*yj + zi*zj);
        if (bi*batch[j] == 0.0f || j == i) d2 = 1e9f;
        else d2 = fmaxf(d2, 0.0f);
        d2s[j] = d2;
    }
    __syncthreads();

    // per-thread candidate over its stripe (j == t mod 256)
    unsigned long long cand = ~0ull;
    #pragma unroll
    for (int it = 0; it < 16; ++it) {
        int j = t + it*256;
        unsigned long long p = ((unsigned long long)__float_as_uint(d2s[j]) << 32) | (unsigned)j;
        cand = min_u64(cand, p);
    }
    for (int k = 0; k < KNBR; ++k) {
        unsigned long long w = cand;
        #pragma unroll
        for (int off = 1; off < 64; off <<= 1)
            w = min_u64(w, shfl_xor_u64(w, off));
        if (lane == 0) wred[k & 1][wave] = w;
        __syncthreads();
        unsigned long long f = min_u64(min_u64(wred[k&1][0], wred[k&1][1]),
                                       min_u64(wred[k&1][2], wred[k&1][3]));
        int sj = (int)(unsigned)f;
        if (t == 0) sel[k] = sj;
        if ((sj & 255) == t) {
            d2s[sj] = 1e9f;     // only the owner thread touches its stripe
            cand = ~0ull;
            #pragma unroll
            for (int it = 0; it < 16; ++it) {
                int j = t + it*256;
                unsigned long long p = ((unsigned long long)__float_as_uint(d2s[j]) << 32) | (unsigned)j;
                cand = min_u64(cand, p);
            }
        }
    }
    __syncthreads();

    if (t < KNBR) {
        int j = sel[t];
        idxs[i*KNBR + t] = j;
        float vx = R[j*3+0]-xi, vy = R[j*3+1]-yi, vz = R[j*3+2]-zi;
        float d = sqrtf(vx*vx + vy*vy + vz*vz + 1e-12f);
        float inv = 1.0f/d;
        vecn[(i*KNBR+t)*3+0] = vx*inv;
        vecn[(i*KNBR+t)*3+1] = vy*inv;
        vecn[(i*KNBR+t)*3+2] = vz*inv;
        const float PI = 3.14159265358979323846f;
        float cutv = (d <= 5.0f) ? 0.5f*(cosf(PI*d*0.2f) + 1.0f) : 0.0f;
        cutw[i*KNBR + t] = cutv;
        for (int jj = 0; jj < NKER; ++jj) {
            float mu = 5.0f * (float)jj / 49.0f;
            float dd = d - mu;
            ebuf[(i*KNBR+t)*NKER + jj] = __expf(-dd*dd*50.0f) * cutv;
        }
    }
}

// ---------------------------------------------------------------------------
// Kernel 2: init s = emb[Z], o = 0, v0 = 0
// ---------------------------------------------------------------------------
__global__ __launch_bounds__(256) void init_kernel(
    const int* __restrict__ Z, const float* __restrict__ emb,
    float* __restrict__ s, float* __restrict__ o, float* __restrict__ v0)
{
    int stride = gridDim.x * blockDim.x;
    for (int idx = blockIdx.x*blockDim.x + threadIdx.x; idx < NATOMS*3*FDIM; idx += stride) {
        v0[idx] = 0.0f;
        if (idx < NATOMS*FDIM) {
            int a = idx >> 7, c = idx & 127;
            s[idx] = emb[Z[a]*FDIM + c];
            o[idx] = 0.0f;
        }
    }
}

// ---------------------------------------------------------------------------
// Kernel W-prep: swizzle WeK/WeV into MFMA B-frag order, bf16 hi/lo
// ---------------------------------------------------------------------------
__global__ __launch_bounds__(64) void wprep_kernel(
    const float* __restrict__ WeK, const float* __restrict__ WeV,
    unsigned short* __restrict__ Wswz)
{
    const int blk = blockIdx.x;
    const int lane = threadIdx.x;
    const int ks = blk & 1;
    const int T  = (blk >> 1) & 31;
    const int l  = blk >> 6;
    const int quad = lane >> 4, x = lane & 15;
    unsigned short* dst = Wswz + (size_t)blk*1024 + lane*8;
    for (int j = 0; j < 8; ++j) {
        int k = ks*32 + quad*8 + j;
        float w = 0.0f;
        if (k < NKER)
            w = (T < 8) ? WeK[l*NKER*FDIM + k*FDIM + T*16 + x]
                        : WeV[(size_t)l*NKER*3*FDIM + k*3*FDIM + (T-8)*16 + x];
        unsigned b = __float_as_uint(w);
        dst[j] = (unsigned short)(b >> 16);
        float r = w - __uint_as_float(b & 0xFFFF0000u);
        dst[512 + j] = (unsigned short)(__float_as_uint(r) >> 16);
    }
}

// ---------------------------------------------------------------------------
// Kernel Q-prep: swizzle [Wq|Wk|Wv] (K=128, N=640) into B-frag bf16 hi/lo
// blk = (l*40 + ct)*4 + ks ; lane holds B[k=ks*32+quad*8+j][col=ct*16+lx]
// ---------------------------------------------------------------------------
__global__ __launch_bounds__(64) void qprep_kernel(
    const float* __restrict__ Wq, const float* __restrict__ Wk,
    const float* __restrict__ Wv, unsigned short* __restrict__ Qswz)
{
    const int blk = blockIdx.x;
    const int lane = threadIdx.x;
    const int ks = blk & 3;
    const int ct = (blk >> 2) % 40;
    const int l  = blk / 160;
    const int quad = lane >> 4, lx = lane & 15;
    const int col = ct*16 + lx;
    unsigned short* dst = Qswz + (size_t)blk*1024 + lane*8;
    for (int j = 0; j < 8; ++j) {
        int k = ks*32 + quad*8 + j;
        float w;
        if (col < 128)      w = Wq[l*16384 + k*128 + col];
        else if (col < 256) w = Wk[l*16384 + k*128 + (col-128)];
        else                w = Wv[(size_t)l*49152 + k*384 + (col-256)];
        unsigned b = __float_as_uint(w);
        dst[j] = (unsigned short)(b >> 16);
        float r = w - __uint_as_float(b & 0xFFFF0000u);
        dst[512 + j] = (unsigned short)(__float_as_uint(r) >> 16);
    }
}

// ---------------------------------------------------------------------------
// Kernel 3 (v2): QKV projection via MFMA bf16 hi/lo.
// grid (256,2) x 128 thr (2 waves). wave: row-tile=blockIdx.x, 10 col-tiles.
// ---------------------------------------------------------------------------
__global__ __launch_bounds__(128) void proj_kernel(
    const float* __restrict__ S, const unsigned short* __restrict__ Qswz,
    float* __restrict__ QKV, int l)
{
    const int rt = blockIdx.x;
    const int t = threadIdx.x, wave = t >> 6, lane = t & 63;
    const int quad = lane >> 4, lx = lane & 15;
    const int cg = blockIdx.y*2 + wave;      // 0..3, each covers 10 col-tiles

    short8 ah[4], al[4];
    const float* srow = S + (size_t)(rt*16 + lx)*FDIM;
    #pragma unroll
    for (int ks = 0; ks < 4; ++ks) {
        float v[8];
        *(f32x4*)&v[0] = *(const f32x4*)(srow + ks*32 + quad*8);
        *(f32x4*)&v[4] = *(const f32x4*)(srow + ks*32 + quad*8 + 4);
        #pragma unroll
        for (int j = 0; j < 8; ++j) {
            unsigned b = __float_as_uint(v[j]);
            ah[ks][j] = (short)(b >> 16);
            float r = v[j] - __uint_as_float(b & 0xFFFF0000u);
            al[ks][j] = (short)(__float_as_uint(r) >> 16);
        }
    }
    for (int ci = 0; ci < 10; ++ci) {
        const int ct = cg*10 + ci;
        const unsigned short* wp = Qswz + (size_t)((l*40 + ct)*4)*1024 + lane*8;
        f32x4 acc = {0.0f, 0.0f, 0.0f, 0.0f};
        #pragma unroll
        for (int ks = 0; ks < 4; ++ks) {
            short8 bh = *(const short8*)(wp + ks*1024);
            short8 bl = *(const short8*)(wp + ks*1024 + 512);
            acc = __builtin_amdgcn_mfma_f32_16x16x32_bf16(ah[ks], bh, acc, 0, 0, 0);
            acc = __builtin_amdgcn_mfma_f32_16x16x32_bf16(ah[ks], bl, acc, 0, 0, 0);
            acc = __builtin_amdgcn_mfma_f32_16x16x32_bf16(al[ks], bh, acc, 0, 0, 0);
        }
        const int col = ct*16 + lx;
        #pragma unroll
        for (int r = 0; r < 4; ++r)
            QKV[(size_t)(rt*16 + quad*4 + r)*QKVW + col] = acc[r];
    }
}

// ---------------------------------------------------------------------------
// Kernel 4 (v3): MFMA edge-filter + attention. 512 threads (8 waves) / atom.
// ---------------------------------------------------------------------------
__global__ __launch_bounds__(512) void attn_kernel(
    const float* __restrict__ QKV, const int* __restrict__ idxs,
    const float* __restrict__ cutw, const float* __restrict__ vecn,
    const float* __restrict__ ebuf, const unsigned short* __restrict__ Wswz,
    const float* __restrict__ beK, const float* __restrict__ beV,
    float* __restrict__ s, float* __restrict__ o,
    const float* __restrict__ vin, float* __restrict__ vout, int l)
{
    __shared__ __align__(16) float es[16][68];
    __shared__ float fbuf[KNBR][516];
    __shared__ int   nidx[KNBR];
    __shared__ float cutv[KNBR];
    __shared__ float vnc[KNBR][3];
    __shared__ float attns[KNBR][NHEAD];
    __shared__ float dvbuf[3][FDIM];

    const int i = blockIdx.x, t = threadIdx.x;
    const int wave = t >> 6, lane = t & 63;
    const int quad = lane >> 4, lx = lane & 15;

    if (t < KNBR) {
        nidx[t] = idxs[i*KNBR + t];
        cutv[t] = cutw[i*KNBR + t];
        vnc[t][0] = vecn[(i*KNBR+t)*3+0];
        vnc[t][1] = vecn[(i*KNBR+t)*3+1];
        vnc[t][2] = vecn[(i*KNBR+t)*3+2];
    }
    for (int x = t; x < 16*64; x += 512) {
        int row = x >> 6, col = x & 63;
        es[row][col] = (row < KNBR && col < NKER)
                       ? ebuf[(size_t)i*KNBR*NKER + row*NKER + col] : 0.0f;
    }
    __syncthreads();

    short8 eh[2], el[2];
    #pragma unroll
    for (int ks = 0; ks < 2; ++ks) {
        float v[8];
        *(f32x4*)&v[0] = *(const f32x4*)&es[lx][ks*32 + quad*8];
        *(f32x4*)&v[4] = *(const f32x4*)&es[lx][ks*32 + quad*8 + 4];
        #pragma unroll
        for (int j = 0; j < 8; ++j) {
            unsigned b = __float_as_uint(v[j]);
            eh[ks][j] = (short)(b >> 16);
            float r = v[j] - __uint_as_float(b & 0xFFFF0000u);
            el[ks][j] = (short)(__float_as_uint(r) >> 16);
        }
    }

    #pragma unroll
    for (int tt = 0; tt < 4; ++tt) {
        const int T = wave*4 + tt;
        const int col = T*16 + lx;
        f32x4 acc = {0.0f, 0.0f, 0.0f, 0.0f};
        #pragma unroll
        for (int ks = 0; ks < 2; ++ks) {
            const unsigned short* wp = Wswz + ((size_t)((l*32+T)*2+ks))*1024 + lane*8;
            short8 bh = *(const short8*)wp;
            short8 bl = *(const short8*)(wp + 512);
            acc = __builtin_amdgcn_mfma_f32_16x16x32_bf16(eh[ks], bh, acc, 0, 0, 0);
            acc = __builtin_amdgcn_mfma_f32_16x16x32_bf16(eh[ks], bl, acc, 0, 0, 0);
            acc = __builtin_amdgcn_mfma_f32_16x16x32_bf16(el[ks], bh, acc, 0, 0, 0);
        }
        const float b = (col < FDIM) ? beK[l*FDIM + col]
                                     : beV[(size_t)l*3*FDIM + (col - FDIM)];
        const int goff = (col < FDIM) ? (FDIM + col) : (2*FDIM + (col - FDIM));
        #pragma unroll
        for (int r = 0; r < 4; ++r) {
            int k = quad*4 + r;
            if (k < KNBR) {
                float f = silu_f(acc[r] + b);
                float g = QKV[(size_t)nidx[k]*QKVW + goff];
                fbuf[k][col] = f * g;
            }
        }
    }
    __syncthreads();

    if (t < FDIM) {
        const int c = t, h = c >> 5;
        const float q = QKV[(size_t)i*QKVW + c];
        float lg[KNBR];
        #pragma unroll
        for (int k = 0; k < KNBR; ++k) {
            float p = q * fbuf[k][c];
            p += __shfl_xor(p, 1);
            p += __shfl_xor(p, 2);
            p += __shfl_xor(p, 4);
            p += __shfl_xor(p, 8);
            p += __shfl_xor(p, 16);
            lg[k] = p * 0.125f;
        }
        float m = -1e30f;
        #pragma unroll
        for (int k = 0; k < KNBR; ++k) m = fmaxf(m, lg[k]);
        float ssum = 0.0f;
        #pragma unroll
        for (int k = 0; k < KNBR; ++k) { lg[k] = __expf(lg[k]-m); ssum += lg[k]; }
        float inv = 1.0f/ssum;
        if ((c & 31) == 0) {
            #pragma unroll
            for (int k = 0; k < KNBR; ++k) attns[k][h] = lg[k]*inv*cutv[k];
        }
    }
    float mval[KNBR];
    int cv = 0, h2 = 0;
    if (t >= FDIM) {
        cv = t - FDIM; h2 = (cv & 127) >> 5;
        #pragma unroll
        for (int k = 0; k < KNBR; ++k) mval[k] = fbuf[k][FDIM + cv];
    }
    __syncthreads();

    if (t >= FDIM) {
        if (cv < FDIM) {
            float ds = 0.0f;
            #pragma unroll
            for (int k = 0; k < KNBR; ++k) ds += attns[k][h2]*mval[k];
            s[i*FDIM + cv] += ds;
            o[i*FDIM + cv] += ds;
        } else if (cv < 2*FDIM) {
            const int cc = cv - FDIM;
            float d0 = 0.0f, d1 = 0.0f, d2 = 0.0f;
            #pragma unroll
            for (int k = 0; k < KNBR; ++k) {
                float w = attns[k][h2]*mval[k];
                d0 += w*vnc[k][0]; d1 += w*vnc[k][1]; d2 += w*vnc[k][2];
            }
            dvbuf[0][cc] = d0; dvbuf[1][cc] = d1; dvbuf[2][cc] = d2;
        }
    }
    float d3[3] = {0.0f, 0.0f, 0.0f};
    if (t >= FDIM && cv >= 2*FDIM) {
        const int cc = cv - 2*FDIM;
        #pragma unroll
        for (int k = 0; k < KNBR; ++k) {
            float w = attns[k][h2]*mval[k];
            const float* vb = vin + (size_t)nidx[k]*3*FDIM + cc;
            d3[0] += w*vb[0*FDIM]; d3[1] += w*vb[1*FDIM]; d3[2] += w*vb[2*FDIM];
        }
    }
    __syncthreads();
    if (t >= FDIM && cv >= 2*FDIM) {
        const int cc = cv - 2*FDIM;
        #pragma unroll
        for (int x = 0; x < 3; ++x) {
            size_t off = (size_t)i*3*FDIM + x*FDIM + cc;
            vout[off] = vin[off] + dvbuf[x][cc] + d3[x];
        }
    }
}

// ---------------------------------------------------------------------------
// Kernel 5: zero output, then LayerNorm + readout, atomicAdd per atom
// ---------------------------------------------------------------------------
__global__ void zero_kernel(float* out) { out[0] = 0.0f; }

__global__ __launch_bounds__(128) void final_kernel(
    const float* __restrict__ o, const float* __restrict__ lng, const float* __restrict__ lnb,
    const float* __restrict__ Wo1, const float* __restrict__ Wo2,
    const float* __restrict__ batch, float* __restrict__ out)
{
    __shared__ float red[128];
    __shared__ float on[128];
    const int i = blockIdx.x, t = threadIdx.x;
    float x = o[i*FDIM + t];
    red[t] = x; __syncthreads();
    for (int off = 64; off > 0; off >>= 1) { if (t < off) red[t] += red[t+off]; __syncthreads(); }
    float mean = red[0] * (1.0f/128.0f);
    __syncthreads();
    float xm = x - mean;
    red[t] = xm*xm; __syncthreads();
    for (int off = 64; off > 0; off >>= 1) { if (t < off) red[t] += red[t+off]; __syncthreads(); }
    float var = red[0] * (1.0f/128.0f);
    __syncthreads();
    on[t] = xm * rsqrtf(var + 1e-5f) * lng[t] + lnb[t];
    __syncthreads();
    float acc = 0.0f;
    #pragma unroll 8
    for (int j = 0; j < 128; ++j) acc += on[j] * Wo1[j*128 + t];
    float h = silu_f(acc) * Wo2[t];
    red[t] = h; __syncthreads();
    for (int off = 64; off > 0; off >>= 1) { if (t < off) red[t] += red[t+off]; __syncthreads(); }
    if (t == 0) atomicAdd(out, red[0] * batch[i]);
}

// ---------------------------------------------------------------------------
extern "C" void kernel_launch(void* const* d_in, const int* in_sizes, int n_in,
                              void* d_out, int out_size, void* d_ws, size_t ws_size,
                              hipStream_t stream)
{
    const int*   Z     = (const int*)  d_in[0];
    const float* R     = (const float*)d_in[1];
    const float* batch = (const float*)d_in[2];
    const float* emb   = (const float*)d_in[3];
    const float* Wq    = (const float*)d_in[4];
    const float* Wk    = (const float*)d_in[5];
    const float* Wv    = (const float*)d_in[6];
    const float* WeK   = (const float*)d_in[7];
    const float* beK   = (const float*)d_in[8];
    const float* WeV   = (const float*)d_in[9];
    const float* beV   = (const float*)d_in[10];
    const float* lng   = (const float*)d_in[11];
    const float* lnb   = (const float*)d_in[12];
    const float* Wo1   = (const float*)d_in[13];
    const float* Wo2   = (const float*)d_in[14];
    float* out = (float*)d_out;

    float* fws = (float*)d_ws;
    float* s    = fws; fws += NATOMS*FDIM;
    float* o    = fws; fws += NATOMS*FDIM;
    float* v0   = fws; fws += NATOMS*3*FDIM;
    float* v1   = fws; fws += NATOMS*3*FDIM;
    float* qkv  = fws; fws += NATOMS*QKVW;
    float* cutw = fws; fws += NATOMS*KNBR;
    float* vecn = fws; fws += NATOMS*KNBR*3;
    float* ebuf = fws; fws += NATOMS*KNBR*NKER;
    int*   idxs = (int*)fws; fws += NATOMS*KNBR;
    unsigned short* Wswz = (unsigned short*)fws;           // 6*32*2*1024 shorts = 768 KB
    fws += (NLAYER*32*2*1024) / 2;
    unsigned short* Qswz = (unsigned short*)fws;           // 6*40*4*1024 shorts = 1.92 MB

    wprep_kernel<<<NLAYER*32*2, 64, 0, stream>>>(WeK, WeV, Wswz);
    qprep_kernel<<<NLAYER*40*4, 64, 0, stream>>>(Wq, Wk, Wv, Qswz);
    knn_kernel<<<NATOMS, 256, 0, stream>>>(R, batch, idxs, cutw, vecn, ebuf);
    init_kernel<<<1024, 256, 0, stream>>>(Z, emb, s, o, v0);
    for (int l = 0; l < NLAYER; ++l) {
        proj_kernel<<<dim3(256, 2), 128, 0, stream>>>(s, Qswz, qkv, l);
        float* vin  = (l & 1) ? v1 : v0;
        float* vout = (l & 1) ? v0 : v1;
        attn_kernel<<<NATOMS, 512, 0, stream>>>(qkv, idxs, cutw, vecn, ebuf, Wswz,
                                                beK, beV, s, o, vin, vout, l);
    }
    zero_kernel<<<1, 1, 0, stream>>>(out);
    final_kernel<<<NATOMS, 128, 0, stream>>>(o, lng, lnb, Wo1, Wo2, batch, out);
}

// Round 5
// 587.828 us; speedup vs baseline: 1.6861x; 1.0575x over previous
//
#include <hip/hip_runtime.h>
#include <math.h>

#define NATOMS 4096
#define FDIM   128
#define NHEAD  4
#define DHEAD  32
#define KNBR   15
#define NKER   50
#define NLAYER 6
#define QKVW   640   // 128 q + 128 k + 384 v

typedef __attribute__((ext_vector_type(8))) short short8;
typedef __attribute__((ext_vector_type(4))) float f32x4;

__device__ __forceinline__ float silu_f(float x) { return x / (1.0f + __expf(-x)); }

__device__ __forceinline__ unsigned long long shfl_xor_u64(unsigned long long v, int m) {
    unsigned lo = (unsigned)v, hi = (unsigned)(v >> 32);
    lo = (unsigned)__shfl_xor((int)lo, m);
    hi = (unsigned)__shfl_xor((int)hi, m);
    return ((unsigned long long)hi << 32) | lo;
}
__device__ __forceinline__ unsigned long long min_u64(unsigned long long a, unsigned long long b) {
    return a < b ? a : b;
}

// ---------------------------------------------------------------------------
// Kernel 1: KNN via packed-u64 shuffle argmin (1 barrier/round) + edges
// ---------------------------------------------------------------------------
__global__ __launch_bounds__(256) void knn_kernel(
    const float* __restrict__ R, const float* __restrict__ batch,
    int* __restrict__ idxs, float* __restrict__ cutw,
    float* __restrict__ vecn, float* __restrict__ ebuf)
{
    __shared__ float d2s[NATOMS];
    __shared__ unsigned long long wred[2][4];
    __shared__ int sel[KNBR];
    const int i = blockIdx.x, t = threadIdx.x;
    const int wave = t >> 6, lane = t & 63;
    const float xi = R[i*3+0], yi = R[i*3+1], zi = R[i*3+2];
    const float bi = batch[i];
    const float sqi = xi*xi + yi*yi + zi*zi;
    for (int j = t; j < NATOMS; j += 256) {
        float xj = R[j*3+0], yj = R[j*3+1], zj = R[j*3+2];
        float sqj = xj*xj + yj*yj + zj*zj;
        float d2 = sqi + sqj - 2.0f*(xi*xj + yi*yj + zi*zj);
        if (bi*batch[j] == 0.0f || j == i) d2 = 1e9f;
        else d2 = fmaxf(d2, 0.0f);
        d2s[j] = d2;
    }
    __syncthreads();

    unsigned long long cand = ~0ull;
    #pragma unroll
    for (int it = 0; it < 16; ++it) {
        int j = t + it*256;
        unsigned long long p = ((unsigned long long)__float_as_uint(d2s[j]) << 32) | (unsigned)j;
        cand = min_u64(cand, p);
    }
    for (int k = 0; k < KNBR; ++k) {
        unsigned long long w = cand;
        #pragma unroll
        for (int off = 1; off < 64; off <<= 1)
            w = min_u64(w, shfl_xor_u64(w, off));
        if (lane == 0) wred[k & 1][wave] = w;
        __syncthreads();
        unsigned long long f = min_u64(min_u64(wred[k&1][0], wred[k&1][1]),
                                       min_u64(wred[k&1][2], wred[k&1][3]));
        int sj = (int)(unsigned)f;
        if (t == 0) sel[k] = sj;
        if ((sj & 255) == t) {
            d2s[sj] = 1e9f;
            cand = ~0ull;
            #pragma unroll
            for (int it = 0; it < 16; ++it) {
                int j = t + it*256;
                unsigned long long p = ((unsigned long long)__float_as_uint(d2s[j]) << 32) | (unsigned)j;
                cand = min_u64(cand, p);
            }
        }
    }
    __syncthreads();

    if (t < KNBR) {
        int j = sel[t];
        idxs[i*KNBR + t] = j;
        float vx = R[j*3+0]-xi, vy = R[j*3+1]-yi, vz = R[j*3+2]-zi;
        float d = sqrtf(vx*vx + vy*vy + vz*vz + 1e-12f);
        float inv = 1.0f/d;
        vecn[(i*KNBR+t)*3+0] = vx*inv;
        vecn[(i*KNBR+t)*3+1] = vy*inv;
        vecn[(i*KNBR+t)*3+2] = vz*inv;
        const float PI = 3.14159265358979323846f;
        float cutv = (d <= 5.0f) ? 0.5f*(cosf(PI*d*0.2f) + 1.0f) : 0.0f;
        cutw[i*KNBR + t] = cutv;
        for (int jj = 0; jj < NKER; ++jj) {
            float mu = 5.0f * (float)jj / 49.0f;
            float dd = d - mu;
            ebuf[(i*KNBR+t)*NKER + jj] = __expf(-dd*dd*50.0f) * cutv;
        }
    }
}

// ---------------------------------------------------------------------------
// Kernel 2: init s = emb[Z], o = 0, v0 = 0
// ---------------------------------------------------------------------------
__global__ __launch_bounds__(256) void init_kernel(
    const int* __restrict__ Z, const float* __restrict__ emb,
    float* __restrict__ s, float* __restrict__ o, float* __restrict__ v0)
{
    int stride = gridDim.x * blockDim.x;
    for (int idx = blockIdx.x*blockDim.x + threadIdx.x; idx < NATOMS*3*FDIM; idx += stride) {
        v0[idx] = 0.0f;
        if (idx < NATOMS*FDIM) {
            int a = idx >> 7, c = idx & 127;
            s[idx] = emb[Z[a]*FDIM + c];
            o[idx] = 0.0f;
        }
    }
}

// ---------------------------------------------------------------------------
// Kernel W-prep: swizzle WeK/WeV into MFMA B-frag order, bf16 hi/lo
// ---------------------------------------------------------------------------
__global__ __launch_bounds__(64) void wprep_kernel(
    const float* __restrict__ WeK, const float* __restrict__ WeV,
    unsigned short* __restrict__ Wswz)
{
    const int blk = blockIdx.x;
    const int lane = threadIdx.x;
    const int ks = blk & 1;
    const int T  = (blk >> 1) & 31;
    const int l  = blk >> 6;
    const int quad = lane >> 4, x = lane & 15;
    unsigned short* dst = Wswz + (size_t)blk*1024 + lane*8;
    for (int j = 0; j < 8; ++j) {
        int k = ks*32 + quad*8 + j;
        float w = 0.0f;
        if (k < NKER)
            w = (T < 8) ? WeK[l*NKER*FDIM + k*FDIM + T*16 + x]
                        : WeV[(size_t)l*NKER*3*FDIM + k*3*FDIM + (T-8)*16 + x];
        unsigned b = __float_as_uint(w);
        dst[j] = (unsigned short)(b >> 16);
        float r = w - __uint_as_float(b & 0xFFFF0000u);
        dst[512 + j] = (unsigned short)(__float_as_uint(r) >> 16);
    }
}

// ---------------------------------------------------------------------------
// Kernel Q-prep: swizzle [Wq|Wk|Wv] (K=128, N=640) into B-frag bf16 hi/lo
// ---------------------------------------------------------------------------
__global__ __launch_bounds__(64) void qprep_kernel(
    const float* __restrict__ Wq, const float* __restrict__ Wk,
    const float* __restrict__ Wv, unsigned short* __restrict__ Qswz)
{
    const int blk = blockIdx.x;
    const int lane = threadIdx.x;
    const int ks = blk & 3;
    const int ct = (blk >> 2) % 40;
    const int l  = blk / 160;
    const int quad = lane >> 4, lx = lane & 15;
    const int col = ct*16 + lx;
    unsigned short* dst = Qswz + (size_t)blk*1024 + lane*8;
    for (int j = 0; j < 8; ++j) {
        int k = ks*32 + quad*8 + j;
        float w;
        if (col < 128)      w = Wq[l*16384 + k*128 + col];
        else if (col < 256) w = Wk[l*16384 + k*128 + (col-128)];
        else                w = Wv[(size_t)l*49152 + k*384 + (col-256)];
        unsigned b = __float_as_uint(w);
        dst[j] = (unsigned short)(b >> 16);
        float r = w - __uint_as_float(b & 0xFFFF0000u);
        dst[512 + j] = (unsigned short)(__float_as_uint(r) >> 16);
    }
}

// ---------------------------------------------------------------------------
// Kernel 3: QKV projection via MFMA bf16 hi/lo
// ---------------------------------------------------------------------------
__global__ __launch_bounds__(128) void proj_kernel(
    const float* __restrict__ S, const unsigned short* __restrict__ Qswz,
    float* __restrict__ QKV, int l)
{
    const int rt = blockIdx.x;
    const int t = threadIdx.x, wave = t >> 6, lane = t & 63;
    const int quad = lane >> 4, lx = lane & 15;
    const int cg = blockIdx.y*2 + wave;

    short8 ah[4], al[4];
    const float* srow = S + (size_t)(rt*16 + lx)*FDIM;
    #pragma unroll
    for (int ks = 0; ks < 4; ++ks) {
        float v[8];
        *(f32x4*)&v[0] = *(const f32x4*)(srow + ks*32 + quad*8);
        *(f32x4*)&v[4] = *(const f32x4*)(srow + ks*32 + quad*8 + 4);
        #pragma unroll
        for (int j = 0; j < 8; ++j) {
            unsigned b = __float_as_uint(v[j]);
            ah[ks][j] = (short)(b >> 16);
            float r = v[j] - __uint_as_float(b & 0xFFFF0000u);
            al[ks][j] = (short)(__float_as_uint(r) >> 16);
        }
    }
    for (int ci = 0; ci < 10; ++ci) {
        const int ct = cg*10 + ci;
        const unsigned short* wp = Qswz + (size_t)((l*40 + ct)*4)*1024 + lane*8;
        f32x4 acc = {0.0f, 0.0f, 0.0f, 0.0f};
        #pragma unroll
        for (int ks = 0; ks < 4; ++ks) {
            short8 bh = *(const short8*)(wp + ks*1024);
            short8 bl = *(const short8*)(wp + ks*1024 + 512);
            acc = __builtin_amdgcn_mfma_f32_16x16x32_bf16(ah[ks], bh, acc, 0, 0, 0);
            acc = __builtin_amdgcn_mfma_f32_16x16x32_bf16(ah[ks], bl, acc, 0, 0, 0);
            acc = __builtin_amdgcn_mfma_f32_16x16x32_bf16(al[ks], bh, acc, 0, 0, 0);
        }
        const int col = ct*16 + lx;
        #pragma unroll
        for (int r = 0; r < 4; ++r)
            QKV[(size_t)(rt*16 + quad*4 + r)*QKVW + col] = acc[r];
    }
}

// ---------------------------------------------------------------------------
// Kernel 4 (v4): MFMA edge-filter + attention, coalesced neighbor staging.
// fbuf is double-purposed: staged neighbor kk/val rows, then filtered in place.
// ---------------------------------------------------------------------------
__global__ __launch_bounds__(512) void attn_kernel(
    const float* __restrict__ QKV, const int* __restrict__ idxs,
    const float* __restrict__ cutw, const float* __restrict__ vecn,
    const float* __restrict__ ebuf, const unsigned short* __restrict__ Wswz,
    const float* __restrict__ beK, const float* __restrict__ beV,
    float* __restrict__ s, float* __restrict__ o,
    const float* __restrict__ vin, float* __restrict__ vout, int l)
{
    __shared__ __align__(16) float es[16][68];
    __shared__ __align__(16) float fbuf[KNBR][516];
    __shared__ int   nidx[KNBR];
    __shared__ float cutv[KNBR];
    __shared__ float vnc[KNBR][3];
    __shared__ float attns[KNBR][NHEAD];
    __shared__ float dvbuf[3][FDIM];

    const int i = blockIdx.x, t = threadIdx.x;
    const int wave = t >> 6, lane = t & 63;
    const int quad = lane >> 4, lx = lane & 15;

    if (t < KNBR) {
        nidx[t] = idxs[i*KNBR + t];
        cutv[t] = cutw[i*KNBR + t];
        vnc[t][0] = vecn[(i*KNBR+t)*3+0];
        vnc[t][1] = vecn[(i*KNBR+t)*3+1];
        vnc[t][2] = vecn[(i*KNBR+t)*3+2];
    }
    for (int x = t; x < 16*64; x += 512) {
        int row = x >> 6, col = x & 63;
        es[row][col] = (row < KNBR && col < NKER)
                       ? ebuf[(size_t)i*KNBR*NKER + row*NKER + col] : 0.0f;
    }
    __syncthreads();   // nidx + es ready

    // ---- coalesced staging of neighbor kk|val rows into fbuf ----
    for (int x = t; x < KNBR*128; x += 512) {
        int k = x >> 7, c4 = x & 127;
        *(f32x4*)&fbuf[k][c4*4] =
            *(const f32x4*)(QKV + (size_t)nidx[k]*QKVW + FDIM + c4*4);
    }

    // ---- A fragments from es ----
    short8 eh[2], el[2];
    #pragma unroll
    for (int ks = 0; ks < 2; ++ks) {
        float v[8];
        *(f32x4*)&v[0] = *(const f32x4*)&es[lx][ks*32 + quad*8];
        *(f32x4*)&v[4] = *(const f32x4*)&es[lx][ks*32 + quad*8 + 4];
        #pragma unroll
        for (int j = 0; j < 8; ++j) {
            unsigned b = __float_as_uint(v[j]);
            eh[ks][j] = (short)(b >> 16);
            float r = v[j] - __uint_as_float(b & 0xFFFF0000u);
            el[ks][j] = (short)(__float_as_uint(r) >> 16);
        }
    }
    __syncthreads();   // staging complete

    // ---- MFMA filter + in-place epilogue ----
    #pragma unroll
    for (int tt = 0; tt < 4; ++tt) {
        const int T = wave*4 + tt;
        const int col = T*16 + lx;
        f32x4 acc = {0.0f, 0.0f, 0.0f, 0.0f};
        #pragma unroll
        for (int ks = 0; ks < 2; ++ks) {
            const unsigned short* wp = Wswz + ((size_t)((l*32+T)*2+ks))*1024 + lane*8;
            short8 bh = *(const short8*)wp;
            short8 bl = *(const short8*)(wp + 512);
            acc = __builtin_amdgcn_mfma_f32_16x16x32_bf16(eh[ks], bh, acc, 0, 0, 0);
            acc = __builtin_amdgcn_mfma_f32_16x16x32_bf16(eh[ks], bl, acc, 0, 0, 0);
            acc = __builtin_amdgcn_mfma_f32_16x16x32_bf16(el[ks], bh, acc, 0, 0, 0);
        }
        const float b = (col < FDIM) ? beK[l*FDIM + col]
                                     : beV[(size_t)l*3*FDIM + (col - FDIM)];
        #pragma unroll
        for (int r = 0; r < 4; ++r) {
            int k = quad*4 + r;
            if (k < KNBR) {
                float f = silu_f(acc[r] + b);
                fbuf[k][col] = f * fbuf[k][col];
            }
        }
    }
    __syncthreads();   // fbuf filtered

    // ---- phase 2: logits + softmax (threads 0..127) ----
    if (t < FDIM) {
        const int c = t, h = c >> 5;
        const float q = QKV[(size_t)i*QKVW + c];
        float lg[KNBR];
        #pragma unroll
        for (int k = 0; k < KNBR; ++k) {
            float p = q * fbuf[k][c];
            p += __shfl_xor(p, 1);
            p += __shfl_xor(p, 2);
            p += __shfl_xor(p, 4);
            p += __shfl_xor(p, 8);
            p += __shfl_xor(p, 16);
            lg[k] = p * 0.125f;
        }
        float m = -1e30f;
        #pragma unroll
        for (int k = 0; k < KNBR; ++k) m = fmaxf(m, lg[k]);
        float ssum = 0.0f;
        #pragma unroll
        for (int k = 0; k < KNBR; ++k) { lg[k] = __expf(lg[k]-m); ssum += lg[k]; }
        float inv = 1.0f/ssum;
        if ((c & 31) == 0) {
            #pragma unroll
            for (int k = 0; k < KNBR; ++k) attns[k][h] = lg[k]*inv*cutv[k];
        }
    }
    float mval[KNBR];
    int cv = 0, h2 = 0;
    if (t >= FDIM) {
        cv = t - FDIM; h2 = (cv & 127) >> 5;
        #pragma unroll
        for (int k = 0; k < KNBR; ++k) mval[k] = fbuf[k][FDIM + cv];
    }
    __syncthreads();

    if (t >= FDIM) {
        if (cv < FDIM) {
            float ds = 0.0f;
            #pragma unroll
            for (int k = 0; k < KNBR; ++k) ds += attns[k][h2]*mval[k];
            s[i*FDIM + cv] += ds;
            o[i*FDIM + cv] += ds;
        } else if (cv < 2*FDIM) {
            const int cc = cv - FDIM;
            float d0 = 0.0f, d1 = 0.0f, d2 = 0.0f;
            #pragma unroll
            for (int k = 0; k < KNBR; ++k) {
                float w = attns[k][h2]*mval[k];
                d0 += w*vnc[k][0]; d1 += w*vnc[k][1]; d2 += w*vnc[k][2];
            }
            dvbuf[0][cc] = d0; dvbuf[1][cc] = d1; dvbuf[2][cc] = d2;
        }
    }
    float d3[3] = {0.0f, 0.0f, 0.0f};
    if (t >= FDIM && cv >= 2*FDIM) {
        const int cc = cv - 2*FDIM;
        #pragma unroll
        for (int k = 0; k < KNBR; ++k) {
            float w = attns[k][h2]*mval[k];
            const float* vb = vin + (size_t)nidx[k]*3*FDIM + cc;
            d3[0] += w*vb[0*FDIM]; d3[1] += w*vb[1*FDIM]; d3[2] += w*vb[2*FDIM];
        }
    }
    __syncthreads();
    if (t >= FDIM && cv >= 2*FDIM) {
        const int cc = cv - 2*FDIM;
        #pragma unroll
        for (int x = 0; x < 3; ++x) {
            size_t off = (size_t)i*3*FDIM + x*FDIM + cc;
            vout[off] = vin[off] + dvbuf[x][cc] + d3[x];
        }
    }
}

// ---------------------------------------------------------------------------
// Kernel 5: LayerNorm + readout -> per-atom scalar (no atomics)
// ---------------------------------------------------------------------------
__global__ __launch_bounds__(128) void final_kernel(
    const float* __restrict__ o, const float* __restrict__ lng, const float* __restrict__ lnb,
    const float* __restrict__ Wo1, const float* __restrict__ Wo2,
    const float* __restrict__ batch, float* __restrict__ hout)
{
    __shared__ float red[128];
    __shared__ float on[128];
    const int i = blockIdx.x, t = threadIdx.x;
    float x = o[i*FDIM + t];
    red[t] = x; __syncthreads();
    for (int off = 64; off > 0; off >>= 1) { if (t < off) red[t] += red[t+off]; __syncthreads(); }
    float mean = red[0] * (1.0f/128.0f);
    __syncthreads();
    float xm = x - mean;
    red[t] = xm*xm; __syncthreads();
    for (int off = 64; off > 0; off >>= 1) { if (t < off) red[t] += red[t+off]; __syncthreads(); }
    float var = red[0] * (1.0f/128.0f);
    __syncthreads();
    on[t] = xm * rsqrtf(var + 1e-5f) * lng[t] + lnb[t];
    __syncthreads();
    float acc = 0.0f;
    #pragma unroll 8
    for (int j = 0; j < 128; ++j) acc += on[j] * Wo1[j*128 + t];
    float h = silu_f(acc) * Wo2[t];
    red[t] = h; __syncthreads();
    for (int off = 64; off > 0; off >>= 1) { if (t < off) red[t] += red[t+off]; __syncthreads(); }
    if (t == 0) hout[i] = red[0] * batch[i];
}

// ---------------------------------------------------------------------------
// Kernel 6: single-block tree reduction of hout[4096] -> out[0]
// ---------------------------------------------------------------------------
__global__ __launch_bounds__(1024) void reduce_kernel(
    const float* __restrict__ hout, float* __restrict__ out)
{
    __shared__ float red[1024];
    const int t = threadIdx.x;
    float a = hout[t] + hout[t+1024] + hout[t+2048] + hout[t+3072];
    red[t] = a; __syncthreads();
    for (int off = 512; off > 0; off >>= 1) {
        if (t < off) red[t] += red[t+off];
        __syncthreads();
    }
    if (t == 0) out[0] = red[0];
}

// ---------------------------------------------------------------------------
extern "C" void kernel_launch(void* const* d_in, const int* in_sizes, int n_in,
                              void* d_out, int out_size, void* d_ws, size_t ws_size,
                              hipStream_t stream)
{
    const int*   Z     = (const int*)  d_in[0];
    const float* R     = (const float*)d_in[1];
    const float* batch = (const float*)d_in[2];
    const float* emb   = (const float*)d_in[3];
    const float* Wq    = (const float*)d_in[4];
    const float* Wk    = (const float*)d_in[5];
    const float* Wv    = (const float*)d_in[6];
    const float* WeK   = (const float*)d_in[7];
    const float* beK   = (const float*)d_in[8];
    const float* WeV   = (const float*)d_in[9];
    const float* beV   = (const float*)d_in[10];
    const float* lng   = (const float*)d_in[11];
    const float* lnb   = (const float*)d_in[12];
    const float* Wo1   = (const float*)d_in[13];
    const float* Wo2   = (const float*)d_in[14];
    float* out = (float*)d_out;

    float* fws = (float*)d_ws;
    float* s    = fws; fws += NATOMS*FDIM;
    float* o    = fws; fws += NATOMS*FDIM;
    float* v0   = fws; fws += NATOMS*3*FDIM;
    float* v1   = fws; fws += NATOMS*3*FDIM;
    float* qkv  = fws; fws += NATOMS*QKVW;
    float* cutw = fws; fws += NATOMS*KNBR;
    float* vecn = fws; fws += NATOMS*KNBR*3;
    float* ebuf = fws; fws += NATOMS*KNBR*NKER;
    float* hout = fws; fws += NATOMS;
    int*   idxs = (int*)fws; fws += NATOMS*KNBR;
    unsigned short* Wswz = (unsigned short*)fws;           // 768 KB
    fws += (NLAYER*32*2*1024) / 2;
    unsigned short* Qswz = (unsigned short*)fws;           // 1.92 MB

    wprep_kernel<<<NLAYER*32*2, 64, 0, stream>>>(WeK, WeV, Wswz);
    qprep_kernel<<<NLAYER*40*4, 64, 0, stream>>>(Wq, Wk, Wv, Qswz);
    knn_kernel<<<NATOMS, 256, 0, stream>>>(R, batch, idxs, cutw, vecn, ebuf);
    init_kernel<<<1024, 256, 0, stream>>>(Z, emb, s, o, v0);
    for (int l = 0; l < NLAYER; ++l) {
        proj_kernel<<<dim3(256, 2), 128, 0, stream>>>(s, Qswz, qkv, l);
        float* vin  = (l & 1) ? v1 : v0;
        float* vout = (l & 1) ? v0 : v1;
        attn_kernel<<<NATOMS, 512, 0, stream>>>(qkv, idxs, cutw, vecn, ebuf, Wswz,
                                                beK, beV, s, o, vin, vout, l);
    }
    final_kernel<<<NATOMS, 128, 0, stream>>>(o, lng, lnb, Wo1, Wo2, batch, hout);
    reduce_kernel<<<1, 1024, 0, stream>>>(hout, out);
}

// Round 6
// 571.339 us; speedup vs baseline: 1.7348x; 1.0289x over previous
//
#include <hip/hip_runtime.h>
#include <math.h>

#define NATOMS 4096
#define FDIM   128
#define NHEAD  4
#define DHEAD  32
#define KNBR   15
#define NKER   50
#define NLAYER 6
#define QKVW   640   // 128 q + 128 k + 384 v

typedef __attribute__((ext_vector_type(8))) short short8;
typedef __attribute__((ext_vector_type(4))) float f32x4;

__device__ __forceinline__ float silu_f(float x) { return x / (1.0f + __expf(-x)); }

__device__ __forceinline__ unsigned long long shfl_xor_u64(unsigned long long v, int m) {
    unsigned lo = (unsigned)v, hi = (unsigned)(v >> 32);
    lo = (unsigned)__shfl_xor((int)lo, m);
    hi = (unsigned)__shfl_xor((int)hi, m);
    return ((unsigned long long)hi << 32) | lo;
}
__device__ __forceinline__ unsigned long long min_u64(unsigned long long a, unsigned long long b) {
    return a < b ? a : b;
}
__device__ __forceinline__ int spread3(int v) {   // 4 bits -> bits 0,3,6,9
    return (v & 1) | ((v & 2) << 2) | ((v & 4) << 4) | ((v & 8) << 6);
}

// ---------------------------------------------------------------------------
// Kernel 0: Morton bucket counting-sort -> perm (rank->id), rank (id->rank)
// single block, 1024 threads; 16^3 grid over the 40^3 box
// ---------------------------------------------------------------------------
__global__ __launch_bounds__(1024) void morton_kernel(
    const float* __restrict__ R, int* __restrict__ perm, int* __restrict__ rank)
{
    __shared__ int hist[4096];
    __shared__ int tscan[1024];
    const int t = threadIdx.x;
    int codes[4];
    #pragma unroll
    for (int u = 0; u < 4; ++u) hist[t*4 + u] = 0;
    __syncthreads();
    #pragma unroll
    for (int u = 0; u < 4; ++u) {
        int i = t + u*1024;
        float x = R[i*3+0], y = R[i*3+1], z = R[i*3+2];
        int cx = min(15, max(0, (int)(x * (16.0f/40.0f))));
        int cy = min(15, max(0, (int)(y * (16.0f/40.0f))));
        int cz = min(15, max(0, (int)(z * (16.0f/40.0f))));
        int code = spread3(cx) | (spread3(cy) << 1) | (spread3(cz) << 2);
        codes[u] = code;
        atomicAdd(&hist[code], 1);
    }
    __syncthreads();
    // blocked exclusive scan of hist[4096]
    int loc[4], s0 = 0;
    #pragma unroll
    for (int u = 0; u < 4; ++u) { loc[u] = hist[t*4 + u]; s0 += loc[u]; }
    tscan[t] = s0;
    __syncthreads();
    for (int off = 1; off < 1024; off <<= 1) {
        int v = tscan[t];
        int a = (t >= off) ? tscan[t - off] : 0;
        __syncthreads();
        tscan[t] = v + a;
        __syncthreads();
    }
    int run = tscan[t] - s0;       // exclusive prefix for this thread's 4 bins
    #pragma unroll
    for (int u = 0; u < 4; ++u) { hist[t*4 + u] = run; run += loc[u]; }
    __syncthreads();
    #pragma unroll
    for (int u = 0; u < 4; ++u) {
        int i = t + u*1024;
        int r = atomicAdd(&hist[codes[u]], 1);
        perm[r] = i;
        rank[i] = r;
    }
}

// ---------------------------------------------------------------------------
// Kernel 1: KNN via packed-u64 shuffle argmin; rank-space output
// block r handles atom perm[r]; neighbors stored as ranks
// ---------------------------------------------------------------------------
__global__ __launch_bounds__(256) void knn_kernel(
    const float* __restrict__ R, const float* __restrict__ batch,
    const int* __restrict__ perm, const int* __restrict__ rank,
    int* __restrict__ idxs, float* __restrict__ cutw,
    float* __restrict__ vecn, float* __restrict__ ebuf)
{
    __shared__ float d2s[NATOMS];
    __shared__ unsigned long long wred[2][4];
    __shared__ int sel[KNBR];
    const int r = blockIdx.x, t = threadIdx.x;
    const int i = perm[r];
    const int wave = t >> 6, lane = t & 63;
    const float xi = R[i*3+0], yi = R[i*3+1], zi = R[i*3+2];
    const float bi = batch[i];
    const float sqi = xi*xi + yi*yi + zi*zi;
    for (int j = t; j < NATOMS; j += 256) {
        float xj = R[j*3+0], yj = R[j*3+1], zj = R[j*3+2];
        float sqj = xj*xj + yj*yj + zj*zj;
        float d2 = sqi + sqj - 2.0f*(xi*xj + yi*yj + zi*zj);
        if (bi*batch[j] == 0.0f || j == i) d2 = 1e9f;
        else d2 = fmaxf(d2, 0.0f);
        d2s[j] = d2;
    }
    __syncthreads();

    unsigned long long cand = ~0ull;
    #pragma unroll
    for (int it = 0; it < 16; ++it) {
        int j = t + it*256;
        unsigned long long p = ((unsigned long long)__float_as_uint(d2s[j]) << 32) | (unsigned)j;
        cand = min_u64(cand, p);
    }
    for (int k = 0; k < KNBR; ++k) {
        unsigned long long w = cand;
        #pragma unroll
        for (int off = 1; off < 64; off <<= 1)
            w = min_u64(w, shfl_xor_u64(w, off));
        if (lane == 0) wred[k & 1][wave] = w;
        __syncthreads();
        unsigned long long f = min_u64(min_u64(wred[k&1][0], wred[k&1][1]),
                                       min_u64(wred[k&1][2], wred[k&1][3]));
        int sj = (int)(unsigned)f;
        if (t == 0) sel[k] = sj;
        if ((sj & 255) == t) {
            d2s[sj] = 1e9f;
            cand = ~0ull;
            #pragma unroll
            for (int it = 0; it < 16; ++it) {
                int j = t + it*256;
                unsigned long long p = ((unsigned long long)__float_as_uint(d2s[j]) << 32) | (unsigned)j;
                cand = min_u64(cand, p);
            }
        }
    }
    __syncthreads();

    if (t < KNBR) {
        int j = sel[t];
        idxs[r*KNBR + t] = rank[j];          // neighbor RANK
        float vx = R[j*3+0]-xi, vy = R[j*3+1]-yi, vz = R[j*3+2]-zi;
        float d = sqrtf(vx*vx + vy*vy + vz*vz + 1e-12f);
        float inv = 1.0f/d;
        vecn[(r*KNBR+t)*3+0] = vx*inv;
        vecn[(r*KNBR+t)*3+1] = vy*inv;
        vecn[(r*KNBR+t)*3+2] = vz*inv;
        const float PI = 3.14159265358979323846f;
        float cutv = (d <= 5.0f) ? 0.5f*(cosf(PI*d*0.2f) + 1.0f) : 0.0f;
        cutw[r*KNBR + t] = cutv;
        for (int jj = 0; jj < NKER; ++jj) {
            float mu = 5.0f * (float)jj / 49.0f;
            float dd = d - mu;
            ebuf[(r*KNBR+t)*NKER + jj] = __expf(-dd*dd*50.0f) * cutv;
        }
    }
}

// ---------------------------------------------------------------------------
// Kernel 2: init s[rank] = emb[Z[perm[rank]]], o = 0, v0 = 0
// ---------------------------------------------------------------------------
__global__ __launch_bounds__(256) void init_kernel(
    const int* __restrict__ Z, const float* __restrict__ emb,
    const int* __restrict__ perm,
    float* __restrict__ s, float* __restrict__ o, float* __restrict__ v0)
{
    int stride = gridDim.x * blockDim.x;
    for (int idx = blockIdx.x*blockDim.x + threadIdx.x; idx < NATOMS*3*FDIM; idx += stride) {
        v0[idx] = 0.0f;
        if (idx < NATOMS*FDIM) {
            int a = idx >> 7, c = idx & 127;
            s[idx] = emb[Z[perm[a]]*FDIM + c];
            o[idx] = 0.0f;
        }
    }
}

// ---------------------------------------------------------------------------
// Kernel W-prep: swizzle WeK/WeV into MFMA B-frag order, bf16 hi/lo
// ---------------------------------------------------------------------------
__global__ __launch_bounds__(64) void wprep_kernel(
    const float* __restrict__ WeK, const float* __restrict__ WeV,
    unsigned short* __restrict__ Wswz)
{
    const int blk = blockIdx.x;
    const int lane = threadIdx.x;
    const int ks = blk & 1;
    const int T  = (blk >> 1) & 31;
    const int l  = blk >> 6;
    const int quad = lane >> 4, x = lane & 15;
    unsigned short* dst = Wswz + (size_t)blk*1024 + lane*8;
    for (int j = 0; j < 8; ++j) {
        int k = ks*32 + quad*8 + j;
        float w = 0.0f;
        if (k < NKER)
            w = (T < 8) ? WeK[l*NKER*FDIM + k*FDIM + T*16 + x]
                        : WeV[(size_t)l*NKER*3*FDIM + k*3*FDIM + (T-8)*16 + x];
        unsigned b = __float_as_uint(w);
        dst[j] = (unsigned short)(b >> 16);
        float r = w - __uint_as_float(b & 0xFFFF0000u);
        dst[512 + j] = (unsigned short)(__float_as_uint(r) >> 16);
    }
}

// ---------------------------------------------------------------------------
// Kernel Q-prep: swizzle [Wq|Wk|Wv] (K=128, N=640) into B-frag bf16 hi/lo
// ---------------------------------------------------------------------------
__global__ __launch_bounds__(64) void qprep_kernel(
    const float* __restrict__ Wq, const float* __restrict__ Wk,
    const float* __restrict__ Wv, unsigned short* __restrict__ Qswz)
{
    const int blk = blockIdx.x;
    const int lane = threadIdx.x;
    const int ks = blk & 3;
    const int ct = (blk >> 2) % 40;
    const int l  = blk / 160;
    const int quad = lane >> 4, lx = lane & 15;
    const int col = ct*16 + lx;
    unsigned short* dst = Qswz + (size_t)blk*1024 + lane*8;
    for (int j = 0; j < 8; ++j) {
        int k = ks*32 + quad*8 + j;
        float w;
        if (col < 128)      w = Wq[l*16384 + k*128 + col];
        else if (col < 256) w = Wk[l*16384 + k*128 + (col-128)];
        else                w = Wv[(size_t)l*49152 + k*384 + (col-256)];
        unsigned b = __float_as_uint(w);
        dst[j] = (unsigned short)(b >> 16);
        float r = w - __uint_as_float(b & 0xFFFF0000u);
        dst[512 + j] = (unsigned short)(__float_as_uint(r) >> 16);
    }
}

// ---------------------------------------------------------------------------
// Kernel 3: QKV projection via MFMA bf16 hi/lo (rank-space rows)
// ---------------------------------------------------------------------------
__global__ __launch_bounds__(128) void proj_kernel(
    const float* __restrict__ S, const unsigned short* __restrict__ Qswz,
    float* __restrict__ QKV, int l)
{
    const int rt = blockIdx.x;
    const int t = threadIdx.x, wave = t >> 6, lane = t & 63;
    const int quad = lane >> 4, lx = lane & 15;
    const int cg = blockIdx.y*2 + wave;

    short8 ah[4], al[4];
    const float* srow = S + (size_t)(rt*16 + lx)*FDIM;
    #pragma unroll
    for (int ks = 0; ks < 4; ++ks) {
        float v[8];
        *(f32x4*)&v[0] = *(const f32x4*)(srow + ks*32 + quad*8);
        *(f32x4*)&v[4] = *(const f32x4*)(srow + ks*32 + quad*8 + 4);
        #pragma unroll
        for (int j = 0; j < 8; ++j) {
            unsigned b = __float_as_uint(v[j]);
            ah[ks][j] = (short)(b >> 16);
            float r = v[j] - __uint_as_float(b & 0xFFFF0000u);
            al[ks][j] = (short)(__float_as_uint(r) >> 16);
        }
    }
    for (int ci = 0; ci < 10; ++ci) {
        const int ct = cg*10 + ci;
        const unsigned short* wp = Qswz + (size_t)((l*40 + ct)*4)*1024 + lane*8;
        f32x4 acc = {0.0f, 0.0f, 0.0f, 0.0f};
        #pragma unroll
        for (int ks = 0; ks < 4; ++ks) {
            short8 bh = *(const short8*)(wp + ks*1024);
            short8 bl = *(const short8*)(wp + ks*1024 + 512);
            acc = __builtin_amdgcn_mfma_f32_16x16x32_bf16(ah[ks], bh, acc, 0, 0, 0);
            acc = __builtin_amdgcn_mfma_f32_16x16x32_bf16(ah[ks], bl, acc, 0, 0, 0);
            acc = __builtin_amdgcn_mfma_f32_16x16x32_bf16(al[ks], bh, acc, 0, 0, 0);
        }
        const int col = ct*16 + lx;
        #pragma unroll
        for (int r = 0; r < 4; ++r)
            QKV[(size_t)(rt*16 + quad*4 + r)*QKVW + col] = acc[r];
    }
}

// ---------------------------------------------------------------------------
// Kernel 4: MFMA edge-filter + attention (rank space, coalesced staging)
// ---------------------------------------------------------------------------
__global__ __launch_bounds__(512) void attn_kernel(
    const float* __restrict__ QKV, const int* __restrict__ idxs,
    const float* __restrict__ cutw, const float* __restrict__ vecn,
    const float* __restrict__ ebuf, const unsigned short* __restrict__ Wswz,
    const float* __restrict__ beK, const float* __restrict__ beV,
    float* __restrict__ s, float* __restrict__ o,
    const float* __restrict__ vin, float* __restrict__ vout, int l)
{
    __shared__ __align__(16) float es[16][68];
    __shared__ __align__(16) float fbuf[KNBR][516];
    __shared__ int   nidx[KNBR];
    __shared__ float cutv[KNBR];
    __shared__ float vnc[KNBR][3];
    __shared__ float attns[KNBR][NHEAD];
    __shared__ float dvbuf[3][FDIM];

    const int i = blockIdx.x, t = threadIdx.x;
    const int wave = t >> 6, lane = t & 63;
    const int quad = lane >> 4, lx = lane & 15;

    if (t < KNBR) {
        nidx[t] = idxs[i*KNBR + t];
        cutv[t] = cutw[i*KNBR + t];
        vnc[t][0] = vecn[(i*KNBR+t)*3+0];
        vnc[t][1] = vecn[(i*KNBR+t)*3+1];
        vnc[t][2] = vecn[(i*KNBR+t)*3+2];
    }
    for (int x = t; x < 16*64; x += 512) {
        int row = x >> 6, col = x & 63;
        es[row][col] = (row < KNBR && col < NKER)
                       ? ebuf[(size_t)i*KNBR*NKER + row*NKER + col] : 0.0f;
    }
    __syncthreads();

    for (int x = t; x < KNBR*128; x += 512) {
        int k = x >> 7, c4 = x & 127;
        *(f32x4*)&fbuf[k][c4*4] =
            *(const f32x4*)(QKV + (size_t)nidx[k]*QKVW + FDIM + c4*4);
    }

    short8 eh[2], el[2];
    #pragma unroll
    for (int ks = 0; ks < 2; ++ks) {
        float v[8];
        *(f32x4*)&v[0] = *(const f32x4*)&es[lx][ks*32 + quad*8];
        *(f32x4*)&v[4] = *(const f32x4*)&es[lx][ks*32 + quad*8 + 4];
        #pragma unroll
        for (int j = 0; j < 8; ++j) {
            unsigned b = __float_as_uint(v[j]);
            eh[ks][j] = (short)(b >> 16);
            float r = v[j] - __uint_as_float(b & 0xFFFF0000u);
            el[ks][j] = (short)(__float_as_uint(r) >> 16);
        }
    }
    __syncthreads();

    #pragma unroll
    for (int tt = 0; tt < 4; ++tt) {
        const int T = wave*4 + tt;
        const int col = T*16 + lx;
        f32x4 acc = {0.0f, 0.0f, 0.0f, 0.0f};
        #pragma unroll
        for (int ks = 0; ks < 2; ++ks) {
            const unsigned short* wp = Wswz + ((size_t)((l*32+T)*2+ks))*1024 + lane*8;
            short8 bh = *(const short8*)wp;
            short8 bl = *(const short8*)(wp + 512);
            acc = __builtin_amdgcn_mfma_f32_16x16x32_bf16(eh[ks], bh, acc, 0, 0, 0);
            acc = __builtin_amdgcn_mfma_f32_16x16x32_bf16(eh[ks], bl, acc, 0, 0, 0);
            acc = __builtin_amdgcn_mfma_f32_16x16x32_bf16(el[ks], bh, acc, 0, 0, 0);
        }
        const float b = (col < FDIM) ? beK[l*FDIM + col]
                                     : beV[(size_t)l*3*FDIM + (col - FDIM)];
        #pragma unroll
        for (int r = 0; r < 4; ++r) {
            int k = quad*4 + r;
            if (k < KNBR) {
                float f = silu_f(acc[r] + b);
                fbuf[k][col] = f * fbuf[k][col];
            }
        }
    }
    __syncthreads();

    if (t < FDIM) {
        const int c = t, h = c >> 5;
        const float q = QKV[(size_t)i*QKVW + c];
        float lg[KNBR];
        #pragma unroll
        for (int k = 0; k < KNBR; ++k) {
            float p = q * fbuf[k][c];
            p += __shfl_xor(p, 1);
            p += __shfl_xor(p, 2);
            p += __shfl_xor(p, 4);
            p += __shfl_xor(p, 8);
            p += __shfl_xor(p, 16);
            lg[k] = p * 0.125f;
        }
        float m = -1e30f;
        #pragma unroll
        for (int k = 0; k < KNBR; ++k) m = fmaxf(m, lg[k]);
        float ssum = 0.0f;
        #pragma unroll
        for (int k = 0; k < KNBR; ++k) { lg[k] = __expf(lg[k]-m); ssum += lg[k]; }
        float inv = 1.0f/ssum;
        if ((c & 31) == 0) {
            #pragma unroll
            for (int k = 0; k < KNBR; ++k) attns[k][h] = lg[k]*inv*cutv[k];
        }
    }
    float mval[KNBR];
    int cv = 0, h2 = 0;
    if (t >= FDIM) {
        cv = t - FDIM; h2 = (cv & 127) >> 5;
        #pragma unroll
        for (int k = 0; k < KNBR; ++k) mval[k] = fbuf[k][FDIM + cv];
    }
    __syncthreads();

    if (t >= FDIM) {
        if (cv < FDIM) {
            float ds = 0.0f;
            #pragma unroll
            for (int k = 0; k < KNBR; ++k) ds += attns[k][h2]*mval[k];
            s[i*FDIM + cv] += ds;
            o[i*FDIM + cv] += ds;
        } else if (cv < 2*FDIM) {
            const int cc = cv - FDIM;
            float d0 = 0.0f, d1 = 0.0f, d2 = 0.0f;
            #pragma unroll
            for (int k = 0; k < KNBR; ++k) {
                float w = attns[k][h2]*mval[k];
                d0 += w*vnc[k][0]; d1 += w*vnc[k][1]; d2 += w*vnc[k][2];
            }
            dvbuf[0][cc] = d0; dvbuf[1][cc] = d1; dvbuf[2][cc] = d2;
        }
    }
    float d3[3] = {0.0f, 0.0f, 0.0f};
    if (t >= FDIM && cv >= 2*FDIM) {
        const int cc = cv - 2*FDIM;
        #pragma unroll
        for (int k = 0; k < KNBR; ++k) {
            float w = attns[k][h2]*mval[k];
            const float* vb = vin + (size_t)nidx[k]*3*FDIM + cc;
            d3[0] += w*vb[0*FDIM]; d3[1] += w*vb[1*FDIM]; d3[2] += w*vb[2*FDIM];
        }
    }
    __syncthreads();
    if (t >= FDIM && cv >= 2*FDIM) {
        const int cc = cv - 2*FDIM;
        #pragma unroll
        for (int x = 0; x < 3; ++x) {
            size_t off = (size_t)i*3*FDIM + x*FDIM + cc;
            vout[off] = vin[off] + dvbuf[x][cc] + d3[x];
        }
    }
}

// ---------------------------------------------------------------------------
// Kernel 5: LayerNorm + readout -> per-atom scalar (rank space)
// ---------------------------------------------------------------------------
__global__ __launch_bounds__(128) void final_kernel(
    const float* __restrict__ o, const float* __restrict__ lng, const float* __restrict__ lnb,
    const float* __restrict__ Wo1, const float* __restrict__ Wo2,
    const float* __restrict__ batch, const int* __restrict__ perm,
    float* __restrict__ hout)
{
    __shared__ float red[128];
    __shared__ float on[128];
    const int i = blockIdx.x, t = threadIdx.x;
    float x = o[i*FDIM + t];
    red[t] = x; __syncthreads();
    for (int off = 64; off > 0; off >>= 1) { if (t < off) red[t] += red[t+off]; __syncthreads(); }
    float mean = red[0] * (1.0f/128.0f);
    __syncthreads();
    float xm = x - mean;
    red[t] = xm*xm; __syncthreads();
    for (int off = 64; off > 0; off >>= 1) { if (t < off) red[t] += red[t+off]; __syncthreads(); }
    float var = red[0] * (1.0f/128.0f);
    __syncthreads();
    on[t] = xm * rsqrtf(var + 1e-5f) * lng[t] + lnb[t];
    __syncthreads();
    float acc = 0.0f;
    #pragma unroll 8
    for (int j = 0; j < 128; ++j) acc += on[j] * Wo1[j*128 + t];
    float h = silu_f(acc) * Wo2[t];
    red[t] = h; __syncthreads();
    for (int off = 64; off > 0; off >>= 1) { if (t < off) red[t] += red[t+off]; __syncthreads(); }
    if (t == 0) hout[i] = red[0] * batch[perm[i]];
}

// ---------------------------------------------------------------------------
// Kernel 6: single-block tree reduction of hout[4096] -> out[0]
// ---------------------------------------------------------------------------
__global__ __launch_bounds__(1024) void reduce_kernel(
    const float* __restrict__ hout, float* __restrict__ out)
{
    __shared__ float red[1024];
    const int t = threadIdx.x;
    float a = hout[t] + hout[t+1024] + hout[t+2048] + hout[t+3072];
    red[t] = a; __syncthreads();
    for (int off = 512; off > 0; off >>= 1) {
        if (t < off) red[t] += red[t+off];
        __syncthreads();
    }
    if (t == 0) out[0] = red[0];
}

// ---------------------------------------------------------------------------
extern "C" void kernel_launch(void* const* d_in, const int* in_sizes, int n_in,
                              void* d_out, int out_size, void* d_ws, size_t ws_size,
                              hipStream_t stream)
{
    const int*   Z     = (const int*)  d_in[0];
    const float* R     = (const float*)d_in[1];
    const float* batch = (const float*)d_in[2];
    const float* emb   = (const float*)d_in[3];
    const float* Wq    = (const float*)d_in[4];
    const float* Wk    = (const float*)d_in[5];
    const float* Wv    = (const float*)d_in[6];
    const float* WeK   = (const float*)d_in[7];
    const float* beK   = (const float*)d_in[8];
    const float* WeV   = (const float*)d_in[9];
    const float* beV   = (const float*)d_in[10];
    const float* lng   = (const float*)d_in[11];
    const float* lnb   = (const float*)d_in[12];
    const float* Wo1   = (const float*)d_in[13];
    const float* Wo2   = (const float*)d_in[14];
    float* out = (float*)d_out;

    float* fws = (float*)d_ws;
    float* s    = fws; fws += NATOMS*FDIM;
    float* o    = fws; fws += NATOMS*FDIM;
    float* v0   = fws; fws += NATOMS*3*FDIM;
    float* v1   = fws; fws += NATOMS*3*FDIM;
    float* qkv  = fws; fws += NATOMS*QKVW;
    float* cutw = fws; fws += NATOMS*KNBR;
    float* vecn = fws; fws += NATOMS*KNBR*3;
    float* ebuf = fws; fws += NATOMS*KNBR*NKER;
    float* hout = fws; fws += NATOMS;
    int*   idxs = (int*)fws; fws += NATOMS*KNBR;
    int*   perm = (int*)fws; fws += NATOMS;
    int*   rank = (int*)fws; fws += NATOMS;
    unsigned short* Wswz = (unsigned short*)fws;           // 768 KB
    fws += (NLAYER*32*2*1024) / 2;
    unsigned short* Qswz = (unsigned short*)fws;           // 1.92 MB

    morton_kernel<<<1, 1024, 0, stream>>>(R, perm, rank);
    wprep_kernel<<<NLAYER*32*2, 64, 0, stream>>>(WeK, WeV, Wswz);
    qprep_kernel<<<NLAYER*40*4, 64, 0, stream>>>(Wq, Wk, Wv, Qswz);
    knn_kernel<<<NATOMS, 256, 0, stream>>>(R, batch, perm, rank, idxs, cutw, vecn, ebuf);
    init_kernel<<<1024, 256, 0, stream>>>(Z, emb, perm, s, o, v0);
    for (int l = 0; l < NLAYER; ++l) {
        proj_kernel<<<dim3(256, 2), 128, 0, stream>>>(s, Qswz, qkv, l);
        float* vin  = (l & 1) ? v1 : v0;
        float* vout = (l & 1) ? v0 : v1;
        attn_kernel<<<NATOMS, 512, 0, stream>>>(qkv, idxs, cutw, vecn, ebuf, Wswz,
                                                beK, beV, s, o, vin, vout, l);
    }
    final_kernel<<<NATOMS, 128, 0, stream>>>(o, lng, lnb, Wo1, Wo2, batch, perm, hout);
    reduce_kernel<<<1, 1024, 0, stream>>>(hout, out);
}

// Round 7
// 520.737 us; speedup vs baseline: 1.9033x; 1.0972x over previous
//
#include <hip/hip_runtime.h>
#include <math.h>

#define NATOMS 4096
#define FDIM   128
#define NHEAD  4
#define DHEAD  32
#define KNBR   15
#define NKER   50
#define NLAYER 6
#define QKVW   640   // 128 q + 128 k + 384 v

typedef __attribute__((ext_vector_type(8))) short short8;
typedef __attribute__((ext_vector_type(4))) float f32x4;

__device__ __forceinline__ float silu_f(float x) { return x / (1.0f + __expf(-x)); }

__device__ __forceinline__ unsigned long long shfl_xor_u64(unsigned long long v, int m) {
    unsigned lo = (unsigned)v, hi = (unsigned)(v >> 32);
    lo = (unsigned)__shfl_xor((int)lo, m);
    hi = (unsigned)__shfl_xor((int)hi, m);
    return ((unsigned long long)hi << 32) | lo;
}
__device__ __forceinline__ unsigned long long min_u64(unsigned long long a, unsigned long long b) {
    return a < b ? a : b;
}
__device__ __forceinline__ int spread3(int v) {   // 4 bits -> bits 0,3,6,9
    return (v & 1) | ((v & 2) << 2) | ((v & 4) << 4) | ((v & 8) << 6);
}

// ---------------------------------------------------------------------------
// Kernel 0: Morton bucket counting-sort -> perm (rank->id), rank (id->rank)
// ---------------------------------------------------------------------------
__global__ __launch_bounds__(1024) void morton_kernel(
    const float* __restrict__ R, int* __restrict__ perm, int* __restrict__ rank)
{
    __shared__ int hist[4096];
    __shared__ int tscan[1024];
    const int t = threadIdx.x;
    int codes[4];
    #pragma unroll
    for (int u = 0; u < 4; ++u) hist[t*4 + u] = 0;
    __syncthreads();
    #pragma unroll
    for (int u = 0; u < 4; ++u) {
        int i = t + u*1024;
        float x = R[i*3+0], y = R[i*3+1], z = R[i*3+2];
        int cx = min(15, max(0, (int)(x * (16.0f/40.0f))));
        int cy = min(15, max(0, (int)(y * (16.0f/40.0f))));
        int cz = min(15, max(0, (int)(z * (16.0f/40.0f))));
        int code = spread3(cx) | (spread3(cy) << 1) | (spread3(cz) << 2);
        codes[u] = code;
        atomicAdd(&hist[code], 1);
    }
    __syncthreads();
    int loc[4], s0 = 0;
    #pragma unroll
    for (int u = 0; u < 4; ++u) { loc[u] = hist[t*4 + u]; s0 += loc[u]; }
    tscan[t] = s0;
    __syncthreads();
    for (int off = 1; off < 1024; off <<= 1) {
        int v = tscan[t];
        int a = (t >= off) ? tscan[t - off] : 0;
        __syncthreads();
        tscan[t] = v + a;
        __syncthreads();
    }
    int run = tscan[t] - s0;
    #pragma unroll
    for (int u = 0; u < 4; ++u) { hist[t*4 + u] = run; run += loc[u]; }
    __syncthreads();
    #pragma unroll
    for (int u = 0; u < 4; ++u) {
        int i = t + u*1024;
        int r = atomicAdd(&hist[codes[u]], 1);
        perm[r] = i;
        rank[i] = r;
    }
}

// ---------------------------------------------------------------------------
// Kernel 1: KNN (rank space) + edge features baked directly into MFMA
// A-fragment format (bf16 hi/lo), layer-invariant -> computed once here.
// eA[r] layout: [grp=ks*2+part][lane][8] shorts, 2048 shorts = 4 KB per atom
// ---------------------------------------------------------------------------
__global__ __launch_bounds__(256) void knn_kernel(
    const float* __restrict__ R, const float* __restrict__ batch,
    const int* __restrict__ perm, const int* __restrict__ rank,
    int* __restrict__ idxs, float* __restrict__ cutw,
    float* __restrict__ vecn, unsigned short* __restrict__ eA)
{
    __shared__ float d2s[NATOMS];
    __shared__ float e_lds[16][64];
    __shared__ unsigned long long wred[2][4];
    __shared__ int sel[KNBR];
    const int r = blockIdx.x, t = threadIdx.x;
    const int i = perm[r];
    const int wave = t >> 6, lane = t & 63;
    const float xi = R[i*3+0], yi = R[i*3+1], zi = R[i*3+2];
    const float bi = batch[i];
    const float sqi = xi*xi + yi*yi + zi*zi;
    for (int x = t; x < 16*64; x += 256) ((float*)e_lds)[x] = 0.0f;
    for (int j = t; j < NATOMS; j += 256) {
        float xj = R[j*3+0], yj = R[j*3+1], zj = R[j*3+2];
        float sqj = xj*xj + yj*yj + zj*zj;
        float d2 = sqi + sqj - 2.0f*(xi*xj + yi*yj + zi*zj);
        if (bi*batch[j] == 0.0f || j == i) d2 = 1e9f;
        else d2 = fmaxf(d2, 0.0f);
        d2s[j] = d2;
    }
    __syncthreads();

    unsigned long long cand = ~0ull;
    #pragma unroll
    for (int it = 0; it < 16; ++it) {
        int j = t + it*256;
        unsigned long long p = ((unsigned long long)__float_as_uint(d2s[j]) << 32) | (unsigned)j;
        cand = min_u64(cand, p);
    }
    for (int k = 0; k < KNBR; ++k) {
        unsigned long long w = cand;
        #pragma unroll
        for (int off = 1; off < 64; off <<= 1)
            w = min_u64(w, shfl_xor_u64(w, off));
        if (lane == 0) wred[k & 1][wave] = w;
        __syncthreads();
        unsigned long long f = min_u64(min_u64(wred[k&1][0], wred[k&1][1]),
                                       min_u64(wred[k&1][2], wred[k&1][3]));
        int sj = (int)(unsigned)f;
        if (t == 0) sel[k] = sj;
        if ((sj & 255) == t) {
            d2s[sj] = 1e9f;
            cand = ~0ull;
            #pragma unroll
            for (int it = 0; it < 16; ++it) {
                int j = t + it*256;
                unsigned long long p = ((unsigned long long)__float_as_uint(d2s[j]) << 32) | (unsigned)j;
                cand = min_u64(cand, p);
            }
        }
    }
    __syncthreads();

    if (t < KNBR) {
        int j = sel[t];
        idxs[r*KNBR + t] = rank[j];
        float vx = R[j*3+0]-xi, vy = R[j*3+1]-yi, vz = R[j*3+2]-zi;
        float d = sqrtf(vx*vx + vy*vy + vz*vz + 1e-12f);
        float inv = 1.0f/d;
        vecn[(r*KNBR+t)*3+0] = vx*inv;
        vecn[(r*KNBR+t)*3+1] = vy*inv;
        vecn[(r*KNBR+t)*3+2] = vz*inv;
        const float PI = 3.14159265358979323846f;
        float cutv = (d <= 5.0f) ? 0.5f*(cosf(PI*d*0.2f) + 1.0f) : 0.0f;
        cutw[r*KNBR + t] = cutv;
        for (int jj = 0; jj < NKER; ++jj) {
            float mu = 5.0f * (float)jj / 49.0f;
            float dd = d - mu;
            e_lds[t][jj] = __expf(-dd*dd*50.0f) * cutv;
        }
    }
    __syncthreads();

    // build layer-invariant MFMA A-fragments: grp = ks*2 + part (part 0=hi,1=lo)
    {
        const int l2 = t & 63, grp = t >> 6;
        const int ks = grp >> 1, part = grp & 1;
        const int lx = l2 & 15, quad = l2 >> 4;
        short8 vv;
        #pragma unroll
        for (int j = 0; j < 8; ++j) {
            float v = e_lds[lx][ks*32 + quad*8 + j];
            unsigned b = __float_as_uint(v);
            if (part == 0) vv[j] = (short)(b >> 16);
            else {
                float rr = v - __uint_as_float(b & 0xFFFF0000u);
                vv[j] = (short)(__float_as_uint(rr) >> 16);
            }
        }
        *(short8*)(eA + (size_t)r*2048 + grp*512 + l2*8) = vv;
    }
}

// ---------------------------------------------------------------------------
// Kernel 2: init s[rank] = emb[Z[perm[rank]]], o = 0, v0 = 0
// ---------------------------------------------------------------------------
__global__ __launch_bounds__(256) void init_kernel(
    const int* __restrict__ Z, const float* __restrict__ emb,
    const int* __restrict__ perm,
    float* __restrict__ s, float* __restrict__ o, float* __restrict__ v0)
{
    int stride = gridDim.x * blockDim.x;
    for (int idx = blockIdx.x*blockDim.x + threadIdx.x; idx < NATOMS*3*FDIM; idx += stride) {
        v0[idx] = 0.0f;
        if (idx < NATOMS*FDIM) {
            int a = idx >> 7, c = idx & 127;
            s[idx] = emb[Z[perm[a]]*FDIM + c];
            o[idx] = 0.0f;
        }
    }
}

// ---------------------------------------------------------------------------
// Kernel W-prep: swizzle WeK/WeV into MFMA B-frag order, bf16 hi/lo
// ---------------------------------------------------------------------------
__global__ __launch_bounds__(64) void wprep_kernel(
    const float* __restrict__ WeK, const float* __restrict__ WeV,
    unsigned short* __restrict__ Wswz)
{
    const int blk = blockIdx.x;
    const int lane = threadIdx.x;
    const int ks = blk & 1;
    const int T  = (blk >> 1) & 31;
    const int l  = blk >> 6;
    const int quad = lane >> 4, x = lane & 15;
    unsigned short* dst = Wswz + (size_t)blk*1024 + lane*8;
    for (int j = 0; j < 8; ++j) {
        int k = ks*32 + quad*8 + j;
        float w = 0.0f;
        if (k < NKER)
            w = (T < 8) ? WeK[l*NKER*FDIM + k*FDIM + T*16 + x]
                        : WeV[(size_t)l*NKER*3*FDIM + k*3*FDIM + (T-8)*16 + x];
        unsigned b = __float_as_uint(w);
        dst[j] = (unsigned short)(b >> 16);
        float r = w - __uint_as_float(b & 0xFFFF0000u);
        dst[512 + j] = (unsigned short)(__float_as_uint(r) >> 16);
    }
}

// ---------------------------------------------------------------------------
// Kernel Q-prep: swizzle [Wq|Wk|Wv] (K=128, N=640) into B-frag bf16 hi/lo
// ---------------------------------------------------------------------------
__global__ __launch_bounds__(64) void qprep_kernel(
    const float* __restrict__ Wq, const float* __restrict__ Wk,
    const float* __restrict__ Wv, unsigned short* __restrict__ Qswz)
{
    const int blk = blockIdx.x;
    const int lane = threadIdx.x;
    const int ks = blk & 3;
    const int ct = (blk >> 2) % 40;
    const int l  = blk / 160;
    const int quad = lane >> 4, lx = lane & 15;
    const int col = ct*16 + lx;
    unsigned short* dst = Qswz + (size_t)blk*1024 + lane*8;
    for (int j = 0; j < 8; ++j) {
        int k = ks*32 + quad*8 + j;
        float w;
        if (col < 128)      w = Wq[l*16384 + k*128 + col];
        else if (col < 256) w = Wk[l*16384 + k*128 + (col-128)];
        else                w = Wv[(size_t)l*49152 + k*384 + (col-256)];
        unsigned b = __float_as_uint(w);
        dst[j] = (unsigned short)(b >> 16);
        float r = w - __uint_as_float(b & 0xFFFF0000u);
        dst[512 + j] = (unsigned short)(__float_as_uint(r) >> 16);
    }
}

// ---------------------------------------------------------------------------
// Kernel 3: QKV projection via MFMA bf16 hi/lo (rank-space rows)
// ---------------------------------------------------------------------------
__global__ __launch_bounds__(128) void proj_kernel(
    const float* __restrict__ S, const unsigned short* __restrict__ Qswz,
    float* __restrict__ QKV, int l)
{
    const int rt = blockIdx.x;
    const int t = threadIdx.x, wave = t >> 6, lane = t & 63;
    const int quad = lane >> 4, lx = lane & 15;
    const int cg = blockIdx.y*2 + wave;

    short8 ah[4], al[4];
    const float* srow = S + (size_t)(rt*16 + lx)*FDIM;
    #pragma unroll
    for (int ks = 0; ks < 4; ++ks) {
        float v[8];
        *(f32x4*)&v[0] = *(const f32x4*)(srow + ks*32 + quad*8);
        *(f32x4*)&v[4] = *(const f32x4*)(srow + ks*32 + quad*8 + 4);
        #pragma unroll
        for (int j = 0; j < 8; ++j) {
            unsigned b = __float_as_uint(v[j]);
            ah[ks][j] = (short)(b >> 16);
            float r = v[j] - __uint_as_float(b & 0xFFFF0000u);
            al[ks][j] = (short)(__float_as_uint(r) >> 16);
        }
    }
    for (int ci = 0; ci < 10; ++ci) {
        const int ct = cg*10 + ci;
        const unsigned short* wp = Qswz + (size_t)((l*40 + ct)*4)*1024 + lane*8;
        f32x4 acc = {0.0f, 0.0f, 0.0f, 0.0f};
        #pragma unroll
        for (int ks = 0; ks < 4; ++ks) {
            short8 bh = *(const short8*)(wp + ks*1024);
            short8 bl = *(const short8*)(wp + ks*1024 + 512);
            acc = __builtin_amdgcn_mfma_f32_16x16x32_bf16(ah[ks], bh, acc, 0, 0, 0);
            acc = __builtin_amdgcn_mfma_f32_16x16x32_bf16(ah[ks], bl, acc, 0, 0, 0);
            acc = __builtin_amdgcn_mfma_f32_16x16x32_bf16(al[ks], bh, acc, 0, 0, 0);
        }
        const int col = ct*16 + lx;
        #pragma unroll
        for (int r = 0; r < 4; ++r)
            QKV[(size_t)(rt*16 + quad*4 + r)*QKVW + col] = acc[r];
    }
}

// ---------------------------------------------------------------------------
// Kernel 4 (v5): MFMA edge-filter + attention.
// Pre-baked A-frags (eA), direct L2-local epilogue gather, 4 barriers,
// phase-C spread over all 512 threads (m3 k-loop split 8/7).
// ---------------------------------------------------------------------------
__global__ __launch_bounds__(512) void attn_kernel(
    const float* __restrict__ QKV, const int* __restrict__ idxs,
    const float* __restrict__ cutw, const float* __restrict__ vecn,
    const unsigned short* __restrict__ eA, const unsigned short* __restrict__ Wswz,
    const float* __restrict__ beK, const float* __restrict__ beV,
    float* __restrict__ s, float* __restrict__ o,
    const float* __restrict__ vin, float* __restrict__ vout, int l)
{
    __shared__ __align__(16) float fbuf[KNBR][516];
    __shared__ int   nidx[KNBR];
    __shared__ float cutv[KNBR];
    __shared__ float vnc[KNBR][3];
    __shared__ float attns[KNBR][NHEAD];
    __shared__ float dvbuf[3][FDIM];
    __shared__ float dvbuf2[3][FDIM];

    const int i = blockIdx.x, t = threadIdx.x;
    const int wave = t >> 6, lane = t & 63;
    const int quad = lane >> 4, lx = lane & 15;

    if (t < KNBR) {
        nidx[t] = idxs[i*KNBR + t];
        cutv[t] = cutw[i*KNBR + t];
        vnc[t][0] = vecn[(i*KNBR+t)*3+0];
        vnc[t][1] = vecn[(i*KNBR+t)*3+1];
        vnc[t][2] = vecn[(i*KNBR+t)*3+2];
    }
    // layer-invariant A-fragments, coalesced 16B loads
    const unsigned short* ea = eA + (size_t)i*2048 + lane*8;
    short8 eh[2], el[2];
    eh[0] = *(const short8*)(ea + 0*512);
    el[0] = *(const short8*)(ea + 1*512);
    eh[1] = *(const short8*)(ea + 2*512);
    el[1] = *(const short8*)(ea + 3*512);
    __syncthreads();   // nidx ready

    // ---- MFMA filter + epilogue with direct gather (Morton-local) ----
    #pragma unroll
    for (int tt = 0; tt < 4; ++tt) {
        const int T = wave*4 + tt;
        const int col = T*16 + lx;
        f32x4 acc = {0.0f, 0.0f, 0.0f, 0.0f};
        #pragma unroll
        for (int ks = 0; ks < 2; ++ks) {
            const unsigned short* wp = Wswz + ((size_t)((l*32+T)*2+ks))*1024 + lane*8;
            short8 bh = *(const short8*)wp;
            short8 bl = *(const short8*)(wp + 512);
            acc = __builtin_amdgcn_mfma_f32_16x16x32_bf16(eh[ks], bh, acc, 0, 0, 0);
            acc = __builtin_amdgcn_mfma_f32_16x16x32_bf16(eh[ks], bl, acc, 0, 0, 0);
            acc = __builtin_amdgcn_mfma_f32_16x16x32_bf16(el[ks], bh, acc, 0, 0, 0);
        }
        const float b = (col < FDIM) ? beK[l*FDIM + col]
                                     : beV[(size_t)l*3*FDIM + (col - FDIM)];
        const int goff = (col < FDIM) ? (FDIM + col) : (2*FDIM + (col - FDIM));
        #pragma unroll
        for (int r = 0; r < 4; ++r) {
            int k = quad*4 + r;
            if (k < KNBR) {
                float f = silu_f(acc[r] + b);
                float g = QKV[(size_t)nidx[k]*QKVW + goff];
                fbuf[k][col] = f * g;
            }
        }
    }
    __syncthreads();   // fbuf filtered

    // ---- logits+softmax on t<128; others preload phase-C operands ----
    float pre[KNBR];
    if (t < FDIM) {
        const int c = t, h = c >> 5;
        const float q = QKV[(size_t)i*QKVW + c];
        float lg[KNBR];
        #pragma unroll
        for (int k = 0; k < KNBR; ++k) {
            float p = q * fbuf[k][c];
            p += __shfl_xor(p, 1);
            p += __shfl_xor(p, 2);
            p += __shfl_xor(p, 4);
            p += __shfl_xor(p, 8);
            p += __shfl_xor(p, 16);
            lg[k] = p * 0.125f;
        }
        float m = -1e30f;
        #pragma unroll
        for (int k = 0; k < KNBR; ++k) m = fmaxf(m, lg[k]);
        float ssum = 0.0f;
        #pragma unroll
        for (int k = 0; k < KNBR; ++k) { lg[k] = __expf(lg[k]-m); ssum += lg[k]; }
        float inv = 1.0f/ssum;
        if ((c & 31) == 0) {
            #pragma unroll
            for (int k = 0; k < KNBR; ++k) attns[k][h] = lg[k]*inv*cutv[k];
        }
    } else if (t < 2*FDIM) {
        const int cc = t - FDIM;
        #pragma unroll
        for (int k = 0; k < KNBR; ++k) pre[k] = fbuf[k][2*FDIM + cc];   // m2
    } else {
        const int cc = (t < 3*FDIM) ? (t - 2*FDIM) : (t - 3*FDIM);
        #pragma unroll
        for (int k = 0; k < KNBR; ++k) pre[k] = fbuf[k][3*FDIM + cc];   // m3
    }
    __syncthreads();   // attns published

    // ---- phase C: all 512 threads ----
    float d3[3] = {0.0f, 0.0f, 0.0f};
    if (t < FDIM) {
        const int c = t, h = c >> 5;
        float ds = 0.0f;
        #pragma unroll
        for (int k = 0; k < KNBR; ++k) ds += attns[k][h]*fbuf[k][FDIM + c];  // m1
        s[i*FDIM + c] += ds;
        o[i*FDIM + c] += ds;
    } else if (t < 2*FDIM) {
        const int cc = t - FDIM, h = cc >> 5;
        float d0 = 0.0f, d1 = 0.0f, d2 = 0.0f;
        #pragma unroll
        for (int k = 0; k < KNBR; ++k) {
            float w = attns[k][h]*pre[k];
            d0 += w*vnc[k][0]; d1 += w*vnc[k][1]; d2 += w*vnc[k][2];
        }
        dvbuf[0][cc] = d0; dvbuf[1][cc] = d1; dvbuf[2][cc] = d2;
    } else if (t < 3*FDIM) {
        const int cc = t - 2*FDIM, h = cc >> 5;
        #pragma unroll
        for (int k = 0; k < 8; ++k) {       // m3, first half of k
            float w = attns[k][h]*pre[k];
            const float* vb = vin + (size_t)nidx[k]*3*FDIM + cc;
            d3[0] += w*vb[0*FDIM]; d3[1] += w*vb[1*FDIM]; d3[2] += w*vb[2*FDIM];
        }
    } else {
        const int cc = t - 3*FDIM, h = cc >> 5;
        float e0 = 0.0f, e1 = 0.0f, e2 = 0.0f;
        #pragma unroll
        for (int k = 8; k < KNBR; ++k) {    // m3, second half of k
            float w = attns[k][h]*pre[k];
            const float* vb = vin + (size_t)nidx[k]*3*FDIM + cc;
            e0 += w*vb[0*FDIM]; e1 += w*vb[1*FDIM]; e2 += w*vb[2*FDIM];
        }
        dvbuf2[0][cc] = e0; dvbuf2[1][cc] = e1; dvbuf2[2][cc] = e2;
    }
    __syncthreads();   // dvbuf/dvbuf2 ready
    if (t >= 2*FDIM && t < 3*FDIM) {
        const int cc = t - 2*FDIM;
        #pragma unroll
        for (int x = 0; x < 3; ++x) {
            size_t off = (size_t)i*3*FDIM + x*FDIM + cc;
            vout[off] = vin[off] + dvbuf[x][cc] + dvbuf2[x][cc] + d3[x];
        }
    }
}

// ---------------------------------------------------------------------------
// Kernel 5: LayerNorm + readout -> per-atom scalar (rank space)
// ---------------------------------------------------------------------------
__global__ __launch_bounds__(128) void final_kernel(
    const float* __restrict__ o, const float* __restrict__ lng, const float* __restrict__ lnb,
    const float* __restrict__ Wo1, const float* __restrict__ Wo2,
    const float* __restrict__ batch, const int* __restrict__ perm,
    float* __restrict__ hout)
{
    __shared__ float red[128];
    __shared__ float on[128];
    const int i = blockIdx.x, t = threadIdx.x;
    float x = o[i*FDIM + t];
    red[t] = x; __syncthreads();
    for (int off = 64; off > 0; off >>= 1) { if (t < off) red[t] += red[t+off]; __syncthreads(); }
    float mean = red[0] * (1.0f/128.0f);
    __syncthreads();
    float xm = x - mean;
    red[t] = xm*xm; __syncthreads();
    for (int off = 64; off > 0; off >>= 1) { if (t < off) red[t] += red[t+off]; __syncthreads(); }
    float var = red[0] * (1.0f/128.0f);
    __syncthreads();
    on[t] = xm * rsqrtf(var + 1e-5f) * lng[t] + lnb[t];
    __syncthreads();
    float acc = 0.0f;
    #pragma unroll 8
    for (int j = 0; j < 128; ++j) acc += on[j] * Wo1[j*128 + t];
    float h = silu_f(acc) * Wo2[t];
    red[t] = h; __syncthreads();
    for (int off = 64; off > 0; off >>= 1) { if (t < off) red[t] += red[t+off]; __syncthreads(); }
    if (t == 0) hout[i] = red[0] * batch[perm[i]];
}

// ---------------------------------------------------------------------------
// Kernel 6: single-block tree reduction of hout[4096] -> out[0]
// ---------------------------------------------------------------------------
__global__ __launch_bounds__(1024) void reduce_kernel(
    const float* __restrict__ hout, float* __restrict__ out)
{
    __shared__ float red[1024];
    const int t = threadIdx.x;
    float a = hout[t] + hout[t+1024] + hout[t+2048] + hout[t+3072];
    red[t] = a; __syncthreads();
    for (int off = 512; off > 0; off >>= 1) {
        if (t < off) red[t] += red[t+off];
        __syncthreads();
    }
    if (t == 0) out[0] = red[0];
}

// ---------------------------------------------------------------------------
extern "C" void kernel_launch(void* const* d_in, const int* in_sizes, int n_in,
                              void* d_out, int out_size, void* d_ws, size_t ws_size,
                              hipStream_t stream)
{
    const int*   Z     = (const int*)  d_in[0];
    const float* R     = (const float*)d_in[1];
    const float* batch = (const float*)d_in[2];
    const float* emb   = (const float*)d_in[3];
    const float* Wq    = (const float*)d_in[4];
    const float* Wk    = (const float*)d_in[5];
    const float* Wv    = (const float*)d_in[6];
    const float* WeK   = (const float*)d_in[7];
    const float* beK   = (const float*)d_in[8];
    const float* WeV   = (const float*)d_in[9];
    const float* beV   = (const float*)d_in[10];
    const float* lng   = (const float*)d_in[11];
    const float* lnb   = (const float*)d_in[12];
    const float* Wo1   = (const float*)d_in[13];
    const float* Wo2   = (const float*)d_in[14];
    float* out = (float*)d_out;

    float* fws = (float*)d_ws;
    float* s    = fws; fws += NATOMS*FDIM;
    float* o    = fws; fws += NATOMS*FDIM;
    float* v0   = fws; fws += NATOMS*3*FDIM;
    float* v1   = fws; fws += NATOMS*3*FDIM;
    float* qkv  = fws; fws += NATOMS*QKVW;
    float* cutw = fws; fws += NATOMS*KNBR;
    float* vecn = fws; fws += NATOMS*KNBR*3;
    float* hout = fws; fws += NATOMS;
    int*   idxs = (int*)fws; fws += NATOMS*KNBR;
    int*   perm = (int*)fws; fws += NATOMS;
    int*   rank = (int*)fws; fws += NATOMS;
    unsigned short* eA   = (unsigned short*)fws;            // 16 MB
    fws += (NATOMS*2048) / 2;
    unsigned short* Wswz = (unsigned short*)fws;            // 768 KB
    fws += (NLAYER*32*2*1024) / 2;
    unsigned short* Qswz = (unsigned short*)fws;            // 1.92 MB

    morton_kernel<<<1, 1024, 0, stream>>>(R, perm, rank);
    wprep_kernel<<<NLAYER*32*2, 64, 0, stream>>>(WeK, WeV, Wswz);
    qprep_kernel<<<NLAYER*40*4, 64, 0, stream>>>(Wq, Wk, Wv, Qswz);
    knn_kernel<<<NATOMS, 256, 0, stream>>>(R, batch, perm, rank, idxs, cutw, vecn, eA);
    init_kernel<<<1024, 256, 0, stream>>>(Z, emb, perm, s, o, v0);
    for (int l = 0; l < NLAYER; ++l) {
        proj_kernel<<<dim3(256, 2), 128, 0, stream>>>(s, Qswz, qkv, l);
        float* vin  = (l & 1) ? v1 : v0;
        float* vout = (l & 1) ? v0 : v1;
        attn_kernel<<<NATOMS, 512, 0, stream>>>(qkv, idxs, cutw, vecn, eA, Wswz,
                                                beK, beV, s, o, vin, vout, l);
    }
    final_kernel<<<NATOMS, 128, 0, stream>>>(o, lng, lnb, Wo1, Wo2, batch, perm, hout);
    reduce_kernel<<<1, 1024, 0, stream>>>(hout, out);
}

// Round 8
// 519.909 us; speedup vs baseline: 1.9064x; 1.0016x over previous
//
#include <hip/hip_runtime.h>
#include <math.h>

#define NATOMS  4096
#define FDIM    128
#define NHEAD   4
#define DHEAD   32
#define KNBR    15
#define NKER    50
#define NLAYER  6
#define QKVW    640   // 128 q + 128 k + 384 v
#define LISTCAP 768

typedef __attribute__((ext_vector_type(8))) short short8;
typedef __attribute__((ext_vector_type(4))) float f32x4;

__device__ __forceinline__ float silu_f(float x) { return x / (1.0f + __expf(-x)); }

__device__ __forceinline__ unsigned long long shfl_xor_u64(unsigned long long v, int m) {
    unsigned lo = (unsigned)v, hi = (unsigned)(v >> 32);
    lo = (unsigned)__shfl_xor((int)lo, m);
    hi = (unsigned)__shfl_xor((int)hi, m);
    return ((unsigned long long)hi << 32) | lo;
}
__device__ __forceinline__ unsigned long long min_u64(unsigned long long a, unsigned long long b) {
    return a < b ? a : b;
}
__device__ __forceinline__ int spread3(int v) {   // 4 bits -> bits 0,3,6,9
    return (v & 1) | ((v & 2) << 2) | ((v & 4) << 4) | ((v & 8) << 6);
}

// ---------------------------------------------------------------------------
// Kernel 0: Morton counting-sort. Exports perm, rank-sorted coords/batch,
// and per-cell CSR offsets (cell_start[4097]) for cell-list KNN.
// ---------------------------------------------------------------------------
__global__ __launch_bounds__(1024) void morton_kernel(
    const float* __restrict__ R, const float* __restrict__ batch,
    int* __restrict__ perm, float* __restrict__ Rs,
    float* __restrict__ batch_s, int* __restrict__ cell_start)
{
    __shared__ int hist[4096];
    __shared__ int tscan[1024];
    const int t = threadIdx.x;
    int codes[4];
    float xs[4], ys[4], zs[4];
    #pragma unroll
    for (int u = 0; u < 4; ++u) hist[t*4 + u] = 0;
    __syncthreads();
    #pragma unroll
    for (int u = 0; u < 4; ++u) {
        int i = t + u*1024;
        float x = R[i*3+0], y = R[i*3+1], z = R[i*3+2];
        xs[u] = x; ys[u] = y; zs[u] = z;
        int cx = min(15, max(0, (int)(x * 0.4f)));
        int cy = min(15, max(0, (int)(y * 0.4f)));
        int cz = min(15, max(0, (int)(z * 0.4f)));
        int code = spread3(cx) | (spread3(cy) << 1) | (spread3(cz) << 2);
        codes[u] = code;
        atomicAdd(&hist[code], 1);
    }
    __syncthreads();
    int loc[4], s0 = 0;
    #pragma unroll
    for (int u = 0; u < 4; ++u) { loc[u] = hist[t*4 + u]; s0 += loc[u]; }
    tscan[t] = s0;
    __syncthreads();
    for (int off = 1; off < 1024; off <<= 1) {
        int v = tscan[t];
        int a = (t >= off) ? tscan[t - off] : 0;
        __syncthreads();
        tscan[t] = v + a;
        __syncthreads();
    }
    int run = tscan[t] - s0;
    #pragma unroll
    for (int u = 0; u < 4; ++u) {
        hist[t*4 + u] = run;
        cell_start[t*4 + u] = run;
        run += loc[u];
    }
    if (t == 0) cell_start[4096] = NATOMS;
    __syncthreads();
    #pragma unroll
    for (int u = 0; u < 4; ++u) {
        int i = t + u*1024;
        int r = atomicAdd(&hist[codes[u]], 1);
        perm[r] = i;
        Rs[r*3+0] = xs[u]; Rs[r*3+1] = ys[u]; Rs[r*3+2] = zs[u];
        batch_s[r] = batch[i];
    }
}

// ---------------------------------------------------------------------------
// Kernel 1 (v3): cell-list KNN, one 64-thread wave per atom (rank space).
// Candidates from 7x7x7 cell neighborhood (guaranteed 7.5A ball >> 15th-NN).
// Wave-level butterfly argmin, no multi-wave barrier rounds.
// Also bakes layer-invariant MFMA A-fragments (bf16 hi/lo) -> eA.
// ---------------------------------------------------------------------------
__global__ __launch_bounds__(64) void knn_kernel(
    const float* __restrict__ Rs, const float* __restrict__ batch_s,
    const int* __restrict__ cell_start,
    int* __restrict__ idxs, float* __restrict__ cutw,
    float* __restrict__ vecn, unsigned short* __restrict__ eA)
{
    __shared__ unsigned long long list[LISTCAP];
    __shared__ int   ridx[LISTCAP];
    __shared__ float e_lds[16][68];   // +4 pad: avoids 16-way bank conflict in eA pack
    __shared__ float dist[KNBR];
    __shared__ float cutl[KNBR];
    __shared__ int   selr[KNBR];
    __shared__ int   cnt;
    const int r = blockIdx.x, t = threadIdx.x;
    if (t == 0) cnt = 0;
    for (int x = t; x < 16*68; x += 64) ((float*)e_lds)[x] = 0.0f;
    const float xi = Rs[r*3+0], yi = Rs[r*3+1], zi = Rs[r*3+2];
    const float bi = batch_s[r];
    const float sqi = xi*xi + yi*yi + zi*zi;
    const int cx = min(15, max(0, (int)(xi * 0.4f)));
    const int cy = min(15, max(0, (int)(yi * 0.4f)));
    const int cz = min(15, max(0, (int)(zi * 0.4f)));
    __syncthreads();

    for (int cid = t; cid < 343; cid += 64) {
        int nx = cx + (cid % 7) - 3;
        int ny = cy + ((cid / 7) % 7) - 3;
        int nz = cz + (cid / 49) - 3;
        if (nx < 0 || nx > 15 || ny < 0 || ny > 15 || nz < 0 || nz > 15) continue;
        int code = spread3(nx) | (spread3(ny) << 1) | (spread3(nz) << 2);
        int s0 = cell_start[code], s1 = cell_start[code + 1];
        for (int r2 = s0; r2 < s1; ++r2) {
            if (r2 == r) continue;
            float xj = Rs[r2*3+0], yj = Rs[r2*3+1], zj = Rs[r2*3+2];
            if (bi * batch_s[r2] == 0.0f) continue;
            float sqj = xj*xj + yj*yj + zj*zj;
            float d2 = sqi + sqj - 2.0f*(xi*xj + yi*yj + zi*zj);
            d2 = fmaxf(d2, 0.0f);
            int slot = atomicAdd(&cnt, 1);
            if (slot < LISTCAP) {
                list[slot] = ((unsigned long long)__float_as_uint(d2) << 32) | (unsigned)slot;
                ridx[slot] = r2;
            }
        }
    }
    __syncthreads();
    const int n = min(cnt, LISTCAP);

    unsigned long long cand = ~0ull;
    for (int idx = t; idx < n; idx += 64) cand = min_u64(cand, list[idx]);
    for (int k = 0; k < KNBR; ++k) {
        unsigned long long w = cand;
        #pragma unroll
        for (int off = 1; off < 64; off <<= 1)
            w = min_u64(w, shfl_xor_u64(w, off));
        int slot = (int)(unsigned)w;
        if (t == 0) selr[k] = ridx[slot];
        if ((slot & 63) == t) {
            list[slot] = ~0ull;
            cand = ~0ull;
            for (int idx = t; idx < n; idx += 64) cand = min_u64(cand, list[idx]);
        }
        __syncthreads();
    }

    if (t < KNBR) {
        int r2 = selr[t];
        idxs[r*KNBR + t] = r2;               // already a rank
        float vx = Rs[r2*3+0]-xi, vy = Rs[r2*3+1]-yi, vz = Rs[r2*3+2]-zi;
        float d = sqrtf(vx*vx + vy*vy + vz*vz + 1e-12f);
        float inv = 1.0f/d;
        vecn[(r*KNBR+t)*3+0] = vx*inv;
        vecn[(r*KNBR+t)*3+1] = vy*inv;
        vecn[(r*KNBR+t)*3+2] = vz*inv;
        const float PI = 3.14159265358979323846f;
        float cutv = (d <= 5.0f) ? 0.5f*(cosf(PI*d*0.2f) + 1.0f) : 0.0f;
        cutw[r*KNBR + t] = cutv;
        dist[t] = d; cutl[t] = cutv;
    }
    __syncthreads();

    for (int x = t; x < KNBR*NKER; x += 64) {
        int k = x / NKER, jj = x % NKER;
        float d = dist[k];
        float mu = 5.0f * (float)jj / 49.0f;
        float dd = d - mu;
        e_lds[k][jj] = __expf(-dd*dd*50.0f) * cutl[k];
    }
    __syncthreads();

    // layer-invariant MFMA A-fragments: grp = ks*2 + part (0=hi,1=lo)
    const int lx = t & 15, quad = t >> 4;
    #pragma unroll
    for (int grp = 0; grp < 4; ++grp) {
        const int ks = grp >> 1, part = grp & 1;
        short8 vv;
        #pragma unroll
        for (int j = 0; j < 8; ++j) {
            float v = e_lds[lx][ks*32 + quad*8 + j];
            unsigned b = __float_as_uint(v);
            if (part == 0) vv[j] = (short)(b >> 16);
            else {
                float rr = v - __uint_as_float(b & 0xFFFF0000u);
                vv[j] = (short)(__float_as_uint(rr) >> 16);
            }
        }
        *(short8*)(eA + (size_t)r*2048 + grp*512 + t*8) = vv;
    }
}

// ---------------------------------------------------------------------------
// Kernel 2: init s[rank] = emb[Z[perm[rank]]], o = 0, v0 = 0
// ---------------------------------------------------------------------------
__global__ __launch_bounds__(256) void init_kernel(
    const int* __restrict__ Z, const float* __restrict__ emb,
    const int* __restrict__ perm,
    float* __restrict__ s, float* __restrict__ o, float* __restrict__ v0)
{
    int stride = gridDim.x * blockDim.x;
    for (int idx = blockIdx.x*blockDim.x + threadIdx.x; idx < NATOMS*3*FDIM; idx += stride) {
        v0[idx] = 0.0f;
        if (idx < NATOMS*FDIM) {
            int a = idx >> 7, c = idx & 127;
            s[idx] = emb[Z[perm[a]]*FDIM + c];
            o[idx] = 0.0f;
        }
    }
}

// ---------------------------------------------------------------------------
// Kernel W-prep: swizzle WeK/WeV into MFMA B-frag order, bf16 hi/lo
// ---------------------------------------------------------------------------
__global__ __launch_bounds__(64) void wprep_kernel(
    const float* __restrict__ WeK, const float* __restrict__ WeV,
    unsigned short* __restrict__ Wswz)
{
    const int blk = blockIdx.x;
    const int lane = threadIdx.x;
    const int ks = blk & 1;
    const int T  = (blk >> 1) & 31;
    const int l  = blk >> 6;
    const int quad = lane >> 4, x = lane & 15;
    unsigned short* dst = Wswz + (size_t)blk*1024 + lane*8;
    for (int j = 0; j < 8; ++j) {
        int k = ks*32 + quad*8 + j;
        float w = 0.0f;
        if (k < NKER)
            w = (T < 8) ? WeK[l*NKER*FDIM + k*FDIM + T*16 + x]
                        : WeV[(size_t)l*NKER*3*FDIM + k*3*FDIM + (T-8)*16 + x];
        unsigned b = __float_as_uint(w);
        dst[j] = (unsigned short)(b >> 16);
        float r = w - __uint_as_float(b & 0xFFFF0000u);
        dst[512 + j] = (unsigned short)(__float_as_uint(r) >> 16);
    }
}

// ---------------------------------------------------------------------------
// Kernel Q-prep: swizzle [Wq|Wk|Wv] (K=128, N=640) into B-frag bf16 hi/lo
// ---------------------------------------------------------------------------
__global__ __launch_bounds__(64) void qprep_kernel(
    const float* __restrict__ Wq, const float* __restrict__ Wk,
    const float* __restrict__ Wv, unsigned short* __restrict__ Qswz)
{
    const int blk = blockIdx.x;
    const int lane = threadIdx.x;
    const int ks = blk & 3;
    const int ct = (blk >> 2) % 40;
    const int l  = blk / 160;
    const int quad = lane >> 4, lx = lane & 15;
    const int col = ct*16 + lx;
    unsigned short* dst = Qswz + (size_t)blk*1024 + lane*8;
    for (int j = 0; j < 8; ++j) {
        int k = ks*32 + quad*8 + j;
        float w;
        if (col < 128)      w = Wq[l*16384 + k*128 + col];
        else if (col < 256) w = Wk[l*16384 + k*128 + (col-128)];
        else                w = Wv[(size_t)l*49152 + k*384 + (col-256)];
        unsigned b = __float_as_uint(w);
        dst[j] = (unsigned short)(b >> 16);
        float r = w - __uint_as_float(b & 0xFFFF0000u);
        dst[512 + j] = (unsigned short)(__float_as_uint(r) >> 16);
    }
}

// ---------------------------------------------------------------------------
// Kernel 3: QKV projection via MFMA bf16 hi/lo (rank-space rows)
// ---------------------------------------------------------------------------
__global__ __launch_bounds__(128) void proj_kernel(
    const float* __restrict__ S, const unsigned short* __restrict__ Qswz,
    float* __restrict__ QKV, int l)
{
    const int rt = blockIdx.x;
    const int t = threadIdx.x, wave = t >> 6, lane = t & 63;
    const int quad = lane >> 4, lx = lane & 15;
    const int cg = blockIdx.y*2 + wave;

    short8 ah[4], al[4];
    const float* srow = S + (size_t)(rt*16 + lx)*FDIM;
    #pragma unroll
    for (int ks = 0; ks < 4; ++ks) {
        float v[8];
        *(f32x4*)&v[0] = *(const f32x4*)(srow + ks*32 + quad*8);
        *(f32x4*)&v[4] = *(const f32x4*)(srow + ks*32 + quad*8 + 4);
        #pragma unroll
        for (int j = 0; j < 8; ++j) {
            unsigned b = __float_as_uint(v[j]);
            ah[ks][j] = (short)(b >> 16);
            float r = v[j] - __uint_as_float(b & 0xFFFF0000u);
            al[ks][j] = (short)(__float_as_uint(r) >> 16);
        }
    }
    for (int ci = 0; ci < 10; ++ci) {
        const int ct = cg*10 + ci;
        const unsigned short* wp = Qswz + (size_t)((l*40 + ct)*4)*1024 + lane*8;
        f32x4 acc = {0.0f, 0.0f, 0.0f, 0.0f};
        #pragma unroll
        for (int ks = 0; ks < 4; ++ks) {
            short8 bh = *(const short8*)(wp + ks*1024);
            short8 bl = *(const short8*)(wp + ks*1024 + 512);
            acc = __builtin_amdgcn_mfma_f32_16x16x32_bf16(ah[ks], bh, acc, 0, 0, 0);
            acc = __builtin_amdgcn_mfma_f32_16x16x32_bf16(ah[ks], bl, acc, 0, 0, 0);
            acc = __builtin_amdgcn_mfma_f32_16x16x32_bf16(al[ks], bh, acc, 0, 0, 0);
        }
        const int col = ct*16 + lx;
        #pragma unroll
        for (int r = 0; r < 4; ++r)
            QKV[(size_t)(rt*16 + quad*4 + r)*QKVW + col] = acc[r];
    }
}

// ---------------------------------------------------------------------------
// Kernel 4 (v6): 2 atoms per block (1024 thr, 16 waves). half = t>>9 runs the
// 512-thread pipeline on atom 2*blockIdx+half. Waves w / w+8 load identical
// weight fragments -> L1 temporal reuse halves weight L2 traffic.
// dv partials live in fbuf's consumed m2 column region (keeps LDS < 64 KB).
// ---------------------------------------------------------------------------
__global__ __launch_bounds__(1024) void attn_kernel(
    const float* __restrict__ QKV, const int* __restrict__ idxs,
    const float* __restrict__ cutw, const float* __restrict__ vecn,
    const unsigned short* __restrict__ eA, const unsigned short* __restrict__ Wswz,
    const float* __restrict__ beK, const float* __restrict__ beV,
    float* __restrict__ s, float* __restrict__ o,
    const float* __restrict__ vin, float* __restrict__ vout, int l)
{
    __shared__ __align__(16) float fbuf[2][KNBR][513];
    __shared__ int   nidx[2][KNBR];
    __shared__ float cutv[2][KNBR];
    __shared__ float vnc[2][KNBR][3];
    __shared__ float attns[2][KNBR][NHEAD];

    const int t = threadIdx.x;
    const int half = t >> 9, tl = t & 511;
    const int i = blockIdx.x*2 + half;
    const int wave = tl >> 6, lane = t & 63;
    const int quad = lane >> 4, lx = lane & 15;

    if (tl < KNBR) {
        nidx[half][tl] = idxs[i*KNBR + tl];
        cutv[half][tl] = cutw[i*KNBR + tl];
        vnc[half][tl][0] = vecn[(i*KNBR+tl)*3+0];
        vnc[half][tl][1] = vecn[(i*KNBR+tl)*3+1];
        vnc[half][tl][2] = vecn[(i*KNBR+tl)*3+2];
    }
    const unsigned short* ea = eA + (size_t)i*2048 + lane*8;
    short8 eh[2], el[2];
    eh[0] = *(const short8*)(ea + 0*512);
    el[0] = *(const short8*)(ea + 1*512);
    eh[1] = *(const short8*)(ea + 2*512);
    el[1] = *(const short8*)(ea + 3*512);
    __syncthreads();   // nidx ready

    // ---- phase A: MFMA filter + epilogue gather ----
    #pragma unroll
    for (int tt = 0; tt < 4; ++tt) {
        const int T = wave*4 + tt;
        const int col = T*16 + lx;
        f32x4 acc = {0.0f, 0.0f, 0.0f, 0.0f};
        #pragma unroll
        for (int ks = 0; ks < 2; ++ks) {
            const unsigned short* wp = Wswz + ((size_t)((l*32+T)*2+ks))*1024 + lane*8;
            short8 bh = *(const short8*)wp;
            short8 bl = *(const short8*)(wp + 512);
            acc = __builtin_amdgcn_mfma_f32_16x16x32_bf16(eh[ks], bh, acc, 0, 0, 0);
            acc = __builtin_amdgcn_mfma_f32_16x16x32_bf16(eh[ks], bl, acc, 0, 0, 0);
            acc = __builtin_amdgcn_mfma_f32_16x16x32_bf16(el[ks], bh, acc, 0, 0, 0);
        }
        const float b = (col < FDIM) ? beK[l*FDIM + col]
                                     : beV[(size_t)l*3*FDIM + (col - FDIM)];
        const int goff = (col < FDIM) ? (FDIM + col) : (2*FDIM + (col - FDIM));
        #pragma unroll
        for (int r = 0; r < 4; ++r) {
            int k = quad*4 + r;
            if (k < KNBR) {
                float f = silu_f(acc[r] + b);
                float g = QKV[(size_t)nidx[half][k]*QKVW + goff];
                fbuf[half][k][col] = f * g;
            }
        }
    }
    __syncthreads();   // fbuf filtered

    // ---- phase B: logits+softmax (tl<128); others preload phase-C operands ----
    float pre[KNBR];
    if (tl < FDIM) {
        const int c = tl, h = c >> 5;
        const float q = QKV[(size_t)i*QKVW + c];
        float lg[KNBR];
        #pragma unroll
        for (int k = 0; k < KNBR; ++k) {
            float p = q * fbuf[half][k][c];
            p += __shfl_xor(p, 1);
            p += __shfl_xor(p, 2);
            p += __shfl_xor(p, 4);
            p += __shfl_xor(p, 8);
            p += __shfl_xor(p, 16);
            lg[k] = p * 0.125f;
        }
        float m = -1e30f;
        #pragma unroll
        for (int k = 0; k < KNBR; ++k) m = fmaxf(m, lg[k]);
        float ssum = 0.0f;
        #pragma unroll
        for (int k = 0; k < KNBR; ++k) { lg[k] = __expf(lg[k]-m); ssum += lg[k]; }
        float inv = 1.0f/ssum;
        if ((c & 31) == 0) {
            #pragma unroll
            for (int k = 0; k < KNBR; ++k) attns[half][k][h] = lg[k]*inv*cutv[half][k];
        }
    } else if (tl < 2*FDIM) {
        const int cc = tl - FDIM;
        #pragma unroll
        for (int k = 0; k < KNBR; ++k) pre[k] = fbuf[half][k][2*FDIM + cc];   // m2
    } else {
        const int cc = (tl < 3*FDIM) ? (tl - 2*FDIM) : (tl - 3*FDIM);
        #pragma unroll
        for (int k = 0; k < KNBR; ++k) pre[k] = fbuf[half][k][3*FDIM + cc];   // m3
    }
    __syncthreads();   // attns published

    // ---- phase C ----
    float d3[3] = {0.0f, 0.0f, 0.0f};
    if (tl < FDIM) {
        const int c = tl, h = c >> 5;
        float ds = 0.0f;
        #pragma unroll
        for (int k = 0; k < KNBR; ++k) ds += attns[half][k][h]*fbuf[half][k][FDIM + c];
        s[i*FDIM + c] += ds;
        o[i*FDIM + c] += ds;
    } else if (tl < 2*FDIM) {
        const int cc = tl - FDIM, h = cc >> 5;
        float d0 = 0.0f, d1 = 0.0f, d2 = 0.0f;
        #pragma unroll
        for (int k = 0; k < KNBR; ++k) {
            float w = attns[half][k][h]*pre[k];
            d0 += w*vnc[half][k][0]; d1 += w*vnc[half][k][1]; d2 += w*vnc[half][k][2];
        }
        fbuf[half][0][2*FDIM + cc] = d0;      // dv partials into consumed m2 region
        fbuf[half][1][2*FDIM + cc] = d1;
        fbuf[half][2][2*FDIM + cc] = d2;
    } else if (tl < 3*FDIM) {
        const int cc = tl - 2*FDIM, h = cc >> 5;
        #pragma unroll
        for (int k = 0; k < 8; ++k) {
            float w = attns[half][k][h]*pre[k];
            const float* vb = vin + (size_t)nidx[half][k]*3*FDIM + cc;
            d3[0] += w*vb[0*FDIM]; d3[1] += w*vb[1*FDIM]; d3[2] += w*vb[2*FDIM];
        }
    } else {
        const int cc = tl - 3*FDIM, h = cc >> 5;
        float e0 = 0.0f, e1 = 0.0f, e2 = 0.0f;
        #pragma unroll
        for (int k = 8; k < KNBR; ++k) {
            float w = attns[half][k][h]*pre[k];
            const float* vb = vin + (size_t)nidx[half][k]*3*FDIM + cc;
            e0 += w*vb[0*FDIM]; e1 += w*vb[1*FDIM]; e2 += w*vb[2*FDIM];
        }
        fbuf[half][3][2*FDIM + cc] = e0;
        fbuf[half][4][2*FDIM + cc] = e1;
        fbuf[half][5][2*FDIM + cc] = e2;
    }
    __syncthreads();   // dv partials ready

    // ---- phase D ----
    if (tl >= 2*FDIM && tl < 3*FDIM) {
        const int cc = tl - 2*FDIM;
        #pragma unroll
        for (int x = 0; x < 3; ++x) {
            size_t off = (size_t)i*3*FDIM + x*FDIM + cc;
            vout[off] = vin[off] + fbuf[half][x][2*FDIM + cc]
                                 + fbuf[half][3+x][2*FDIM + cc] + d3[x];
        }
    }
}

// ---------------------------------------------------------------------------
// Kernel 5: LayerNorm + readout -> per-atom scalar (rank space)
// ---------------------------------------------------------------------------
__global__ __launch_bounds__(128) void final_kernel(
    const float* __restrict__ o, const float* __restrict__ lng, const float* __restrict__ lnb,
    const float* __restrict__ Wo1, const float* __restrict__ Wo2,
    const float* __restrict__ batch, const int* __restrict__ perm,
    float* __restrict__ hout)
{
    __shared__ float red[128];
    __shared__ float on[128];
    const int i = blockIdx.x, t = threadIdx.x;
    float x = o[i*FDIM + t];
    red[t] = x; __syncthreads();
    for (int off = 64; off > 0; off >>= 1) { if (t < off) red[t] += red[t+off]; __syncthreads(); }
    float mean = red[0] * (1.0f/128.0f);
    __syncthreads();
    float xm = x - mean;
    red[t] = xm*xm; __syncthreads();
    for (int off = 64; off > 0; off >>= 1) { if (t < off) red[t] += red[t+off]; __syncthreads(); }
    float var = red[0] * (1.0f/128.0f);
    __syncthreads();
    on[t] = xm * rsqrtf(var + 1e-5f) * lng[t] + lnb[t];
    __syncthreads();
    float acc = 0.0f;
    #pragma unroll 8
    for (int j = 0; j < 128; ++j) acc += on[j] * Wo1[j*128 + t];
    float h = silu_f(acc) * Wo2[t];
    red[t] = h; __syncthreads();
    for (int off = 64; off > 0; off >>= 1) { if (t < off) red[t] += red[t+off]; __syncthreads(); }
    if (t == 0) hout[i] = red[0] * batch[perm[i]];
}

// ---------------------------------------------------------------------------
// Kernel 6: single-block tree reduction of hout[4096] -> out[0]
// ---------------------------------------------------------------------------
__global__ __launch_bounds__(1024) void reduce_kernel(
    const float* __restrict__ hout, float* __restrict__ out)
{
    __shared__ float red[1024];
    const int t = threadIdx.x;
    float a = hout[t] + hout[t+1024] + hout[t+2048] + hout[t+3072];
    red[t] = a; __syncthreads();
    for (int off = 512; off > 0; off >>= 1) {
        if (t < off) red[t] += red[t+off];
        __syncthreads();
    }
    if (t == 0) out[0] = red[0];
}

// ---------------------------------------------------------------------------
extern "C" void kernel_launch(void* const* d_in, const int* in_sizes, int n_in,
                              void* d_out, int out_size, void* d_ws, size_t ws_size,
                              hipStream_t stream)
{
    const int*   Z     = (const int*)  d_in[0];
    const float* R     = (const float*)d_in[1];
    const float* batch = (const float*)d_in[2];
    const float* emb   = (const float*)d_in[3];
    const float* Wq    = (const float*)d_in[4];
    const float* Wk    = (const float*)d_in[5];
    const float* Wv    = (const float*)d_in[6];
    const float* WeK   = (const float*)d_in[7];
    const float* beK   = (const float*)d_in[8];
    const float* WeV   = (const float*)d_in[9];
    const float* beV   = (const float*)d_in[10];
    const float* lng   = (const float*)d_in[11];
    const float* lnb   = (const float*)d_in[12];
    const float* Wo1   = (const float*)d_in[13];
    const float* Wo2   = (const float*)d_in[14];
    float* out = (float*)d_out;

    float* fws = (float*)d_ws;
    float* s    = fws; fws += NATOMS*FDIM;
    float* o    = fws; fws += NATOMS*FDIM;
    float* v0   = fws; fws += NATOMS*3*FDIM;
    float* v1   = fws; fws += NATOMS*3*FDIM;
    float* qkv  = fws; fws += NATOMS*QKVW;
    float* cutw = fws; fws += NATOMS*KNBR;
    float* vecn = fws; fws += NATOMS*KNBR*3;
    float* hout = fws; fws += NATOMS;
    float* Rs   = fws; fws += NATOMS*3;
    float* bsrt = fws; fws += NATOMS;
    int*   idxs = (int*)fws; fws += NATOMS*KNBR;
    int*   perm = (int*)fws; fws += NATOMS;
    int*   cells= (int*)fws; fws += 4097;
    fws += 3;   // realign
    unsigned short* eA   = (unsigned short*)fws;            // 16 MB
    fws += (NATOMS*2048) / 2;
    unsigned short* Wswz = (unsigned short*)fws;            // 768 KB
    fws += (NLAYER*32*2*1024) / 2;
    unsigned short* Qswz = (unsigned short*)fws;            // 1.92 MB

    morton_kernel<<<1, 1024, 0, stream>>>(R, batch, perm, Rs, bsrt, cells);
    wprep_kernel<<<NLAYER*32*2, 64, 0, stream>>>(WeK, WeV, Wswz);
    qprep_kernel<<<NLAYER*40*4, 64, 0, stream>>>(Wq, Wk, Wv, Qswz);
    knn_kernel<<<NATOMS, 64, 0, stream>>>(Rs, bsrt, cells, idxs, cutw, vecn, eA);
    init_kernel<<<1024, 256, 0, stream>>>(Z, emb, perm, s, o, v0);
    for (int l = 0; l < NLAYER; ++l) {
        proj_kernel<<<dim3(256, 2), 128, 0, stream>>>(s, Qswz, qkv, l);
        float* vin  = (l & 1) ? v1 : v0;
        float* vout = (l & 1) ? v0 : v1;
        attn_kernel<<<NATOMS/2, 1024, 0, stream>>>(qkv, idxs, cutw, vecn, eA, Wswz,
                                                   beK, beV, s, o, vin, vout, l);
    }
    final_kernel<<<NATOMS, 128, 0, stream>>>(o, lng, lnb, Wo1, Wo2, batch, perm, hout);
    reduce_kernel<<<1, 1024, 0, stream>>>(hout, out);
}